// Round 11
// baseline (268.746 us; speedup 1.0000x reference)
//
#include <hip/hip_runtime.h>

typedef unsigned short u16;
typedef unsigned short u16x8 __attribute__((ext_vector_type(8)));
typedef unsigned short u16x4 __attribute__((ext_vector_type(4)));
typedef unsigned int   u32x2 __attribute__((ext_vector_type(2)));
typedef short          s16x8 __attribute__((ext_vector_type(8)));
typedef float          f32x4 __attribute__((ext_vector_type(4)));

#define DEV static __device__ __forceinline__

DEV float bf2f(u16 u){ unsigned int v = ((unsigned int)u) << 16; return __builtin_bit_cast(float, v); }
DEV u16 f2bf(float f){
  unsigned int u = __builtin_bit_cast(unsigned int, f);
  u += 0x7fffu + ((u >> 16) & 1u);
  return (u16)(u >> 16);
}

DEV f32x4 mfma16(u16x8 a, u16x8 b, f32x4 c){
  return __builtin_amdgcn_mfma_f32_16x16x32_bf16(
      __builtin_bit_cast(s16x8, a), __builtin_bit_cast(s16x8, b), c, 0, 0, 0);
}

// async global->LDS, 16B per lane; lds dest must be wave-uniform base
DEV void g2l16(const void* g, void* l){
  __builtin_amdgcn_global_load_lds((const __attribute__((address_space(1))) void*)g,
                                   (__attribute__((address_space(3))) void*)l, 16, 0, 0);
}

// token t (windowed order) -> float offset of its 256-channel row in x / out [B,56,56,256]
DEV size_t xrow_from(int b, int hw){
  int h1 = hw / 7, w1 = hw - h1 * 7;
  return ((size_t)(((b >> 6) * 56 + h1 * 8 + ((b >> 3) & 7)) * 56 + (w1 * 8 + (b & 7)))) << 8;
}
DEV size_t xrow_off(int t){ int b = t / 49; return xrow_from(b, t - b * 49); }

// ---------------- K0: weight prep ----------------
__global__ __launch_bounds__(256) void k_prep(const float* __restrict__ qkvw,
                                              const float* __restrict__ c3,
                                              const float* __restrict__ c5,
                                              const float* __restrict__ c7,
                                              const float* __restrict__ fin,
                                              const float* __restrict__ fout,
                                              u16* __restrict__ wq, u16* __restrict__ wfi,
                                              u16* __restrict__ wfo, float* __restrict__ weffT){
  int id = blockIdx.x * 256 + threadIdx.x;
  if (id < 196608) { wq[id] = f2bf(qkvw[id]); return; }
  id -= 196608;
  if (id < 65536) { wfi[id] = f2bf(fin[id]); return; }
  id -= 65536;
  if (id < 65536) { wfo[id] = f2bf(fout[id]); return; }
  id -= 65536;
  if (id < 12544) {
    int c = id / 49, t = id - c * 49;
    int di = t / 7 - 3, dj = t % 7 - 3;
    float s = c7[c * 49 + t];
    if (di >= -2 && di <= 2 && dj >= -2 && dj <= 2) s += c5[c * 25 + (di + 2) * 5 + (dj + 2)];
    if (di >= -1 && di <= 1 && dj >= -1 && dj <= 1) s += c3[c * 9 + (di + 1) * 3 + (dj + 1)];
    weffT[c * 52 + t] = 0.05f * s;   // BETA*0.25 folded; [channel][49 taps], stride 52
  }
}

// ---------------- K0b: x -> bf16 windowed layout xbf[t][256] ----------------
__global__ __launch_bounds__(256) void k_xbf(const float* __restrict__ x, u16* __restrict__ xbf){
  int tid = threadIdx.x;
  int tok = blockIdx.x * 4 + (tid >> 6);
  int c4 = (tid & 63) * 4;
  float4 v = *(const float4*)(x + xrow_off(tok) + c4);
  u16x4 o; o[0] = f2bf(v.x); o[1] = f2bf(v.y); o[2] = f2bf(v.z); o[3] = f2bf(v.w);
  *(u16x4*)&xbf[(size_t)tok * 256 + c4] = o;
}

// ---------------- K1: QKV GEMM  M=100352 N=768 K=256 (flat [t][256] epilogue) ----------------
__global__ __launch_bounds__(256) void k_qkv(const u16* __restrict__ xbf,
                                             const u16* __restrict__ wq,
                                             const float* __restrict__ qkvb,
                                             u16* __restrict__ qb, u16* __restrict__ kb,
                                             u16* __restrict__ vmb){
  __shared__ __align__(16) u16 As[128 * 64];
  __shared__ __align__(16) u16 Bs[128 * 64];
  const int bid = blockIdx.x;
  const int lin = (bid & 7) * 588 + (bid >> 3);  // XCD-chunk swizzle (4704 = 8*588)
  const int bm = lin / 6, bn = lin - bm * 6;
  const int tid = threadIdx.x, lane = tid & 63, wid = tid >> 6;
  const int wm = wid >> 1, wn = wid & 1;
  const int r = lane & 15, g = lane >> 4;
  const int lr = lane >> 3;
  const int swz = ((lane & 7) ^ lr) * 16;        // pre-swizzled global source block
  const f32x4 fz = {0.f, 0.f, 0.f, 0.f};
  f32x4 acc[4][4];
#pragma unroll
  for (int m = 0; m < 4; ++m)
#pragma unroll
    for (int n = 0; n < 4; ++n) acc[m][n] = fz;

  const char* gA0 = (const char*)xbf + (size_t)bm * 128 * 512;
  const char* gB0 = (const char*)wq  + (size_t)bn * 128 * 512;

  for (int kt = 0; kt < 4; ++kt) {
#pragma unroll
    for (int ri = 0; ri < 4; ++ri) {
      int chunk = ri * 4 + wid;
      int row = chunk * 8 + lr;
      g2l16(gA0 + (size_t)row * 512 + kt * 128 + swz, (char*)As + chunk * 1024);
      g2l16(gB0 + (size_t)row * 512 + kt * 128 + swz, (char*)Bs + chunk * 1024);
    }
    __syncthreads();
#pragma unroll
    for (int kk = 0; kk < 2; ++kk) {
      u16x8 af[4], bq[4];
#pragma unroll
      for (int m = 0; m < 4; ++m)
        af[m] = *(const u16x8*)&As[(wm * 64 + m * 16 + r) * 64 + (((kk * 4 + g) ^ (r & 7)) * 8)];
#pragma unroll
      for (int n = 0; n < 4; ++n)
        bq[n] = *(const u16x8*)&Bs[(wn * 64 + n * 16 + r) * 64 + (((kk * 4 + g) ^ (r & 7)) * 8)];
#pragma unroll
      for (int m = 0; m < 4; ++m)
#pragma unroll
        for (int n = 0; n < 4; ++n) acc[m][n] = mfma16(af[m], bq[n], acc[m][n]);
    }
    __syncthreads();
  }

  // epilogue: flat [t][256] stores, no divisions
  const int sec = bn >> 1;                       // 0=q 1=k 2=v
  const int cb = (bn & 1) * 128 + wn * 64;       // section-local col base
  u16* const outp = (sec == 0) ? qb : (sec == 1) ? kb : vmb;
  float bias[4];
#pragma unroll
  for (int n = 0; n < 4; ++n) bias[n] = qkvb[sec * 256 + cb + n * 16 + r];
#pragma unroll
  for (int m = 0; m < 4; ++m) {
#pragma unroll
    for (int i = 0; i < 4; ++i) {
      int t = bm * 128 + wm * 64 + m * 16 + g * 4 + i;
      u16* dst = outp + (size_t)t * 256 + cb;
      if (sec == 0) {
#pragma unroll
        for (int n = 0; n < 4; ++n) dst[n * 16 + r] = f2bf((acc[m][n][i] + bias[n]) * 0.125f);
      } else if (sec == 1) {
#pragma unroll
        for (int n = 0; n < 4; ++n) dst[n * 16 + r] = f2bf(acc[m][n][i] + bias[n]);
      } else {
        const u16* xsrc = xbf + (size_t)t * 256 + cb;
#pragma unroll
        for (int n = 0; n < 4; ++n)
          dst[n * 16 + r] = f2bf(0.1f * (acc[m][n][i] + bias[n]) + bf2f(xsrc[n * 16 + r]));
      }
    }
  }
}

// ---------------- K2: attention + conv + combine (no Q/K LDS staging; flat xo [t][256]) ----------------
template<int HW0, int NPIX>
DEV void conv_do(const float (&in_f)[49], const float (&wreg)[49], const u16* xs,
                 int c, size_t obase, u16* __restrict__ xo){
#pragma unroll
  for (int p = 0; p < NPIX; ++p) {
    const int hw = HW0 + p;
    const int i0 = hw / 7, j0 = hw % 7;
    float a = 0.f;
#pragma unroll
    for (int di = -3; di <= 3; ++di) {
      const int ii = i0 + di;
      if (ii < 0 || ii > 6) continue;
#pragma unroll
      for (int dj = -3; dj <= 3; ++dj) {
        const int jj = j0 + dj;
        if (jj < 0 || jj > 6) continue;
        a += in_f[ii * 7 + jj] * wreg[(di + 3) * 7 + (dj + 3)];
      }
    }
    float xsv = bf2f(xs[hw * 72 + c]);
    float outv = in_f[hw] + 0.05f * xsv + a;
    xo[obase + (size_t)hw * 256] = f2bf(outv);
  }
}

__global__ __launch_bounds__(256) void k_attn(const u16* __restrict__ qb,
                                              const u16* __restrict__ kb,
                                              const u16* __restrict__ vmb,
                                              const float* __restrict__ weffT,
                                              u16* __restrict__ xo){
  __shared__ __align__(16) u16 smem[18432];   // per head: Vt 64*72 @hl*9216, P 64*72 @+4608
  const int bx = blockIdx.x;
  const int b = bx >> 1, hp = bx & 1;
  const int tid = threadIdx.x, lane = tid & 63, wid = tid >> 6;
  const int hl = wid >> 1, hf = wid & 1;      // head_local, half
  const int hg = hp * 2 + hl;                 // global head
  const int vto = hl * 9216, po = hl * 9216 + 4608;
  const int r = lane & 15, g = lane >> 4;
  const size_t tok0 = (size_t)b * 49;         // first token of window
  const int hc = hg * 64;                     // head channel base

  if (hf == 0) {
    // stage v transposed: vT[d][key], keys 49..63 zeroed
    int c = lane;
    u16 pix[49];
#pragma unroll
    for (int hw = 0; hw < 49; ++hw) pix[hw] = vmb[(tok0 + hw) * 256 + hc + c];
#pragma unroll
    for (int t2 = 0; t2 < 12; ++t2) {
      u32x2 w;
      w[0] = (unsigned)pix[4 * t2] | ((unsigned)pix[4 * t2 + 1] << 16);
      w[1] = (unsigned)pix[4 * t2 + 2] | ((unsigned)pix[4 * t2 + 3] << 16);
      *(u32x2*)&smem[vto + c * 72 + 4 * t2] = w;
    }
    u32x2 wl; wl[0] = (unsigned)pix[48]; wl[1] = 0u;
    *(u32x2*)&smem[vto + c * 72 + 48] = wl;
    u32x2 z; z[0] = 0u; z[1] = 0u;
    *(u32x2*)&smem[vto + c * 72 + 52] = z;
    *(u32x2*)&smem[vto + c * 72 + 56] = z;
    *(u32x2*)&smem[vto + c * 72 + 60] = z;
  }

  // ---- S = Q K^T, fragments loaded directly global->VGPR ----
  const int mt0 = hf * 2;
  const f32x4 fz = {0.f, 0.f, 0.f, 0.f};
  f32x4 s[2][4];
#pragma unroll
  for (int m = 0; m < 2; ++m)
#pragma unroll
    for (int n = 0; n < 4; ++n) s[m][n] = fz;
  u16x8 aq[2][2], bk[4][2];
#pragma unroll
  for (int m = 0; m < 2; ++m) {
    int qrow = (mt0 + m) * 16 + r; if (qrow > 48) qrow = 48;   // junk rows -> dup, never read
    const u16* src = qb + (tok0 + qrow) * 256 + hc;
    aq[m][0] = *(const u16x8*)(src + g * 8);
    aq[m][1] = *(const u16x8*)(src + 32 + g * 8);
  }
#pragma unroll
  for (int n = 0; n < 4; ++n) {
    int krow = n * 16 + r; if (krow > 48) krow = 0;            // junk keys masked below
    const u16* src = kb + (tok0 + krow) * 256 + hc;
    bk[n][0] = *(const u16x8*)(src + g * 8);
    bk[n][1] = *(const u16x8*)(src + 32 + g * 8);
  }
#pragma unroll
  for (int kk = 0; kk < 2; ++kk)
#pragma unroll
    for (int m = 0; m < 2; ++m)
#pragma unroll
      for (int n = 0; n < 4; ++n) s[m][n] = mfma16(aq[m][kk], bk[n][kk], s[m][n]);

  // ---- softmax (rows = queries), mask cols >= 49, write P bf16 ----
#pragma unroll
  for (int m = 0; m < 2; ++m) {
#pragma unroll
    for (int i = 0; i < 4; ++i) {
      float x0 = s[m][0][i], x1 = s[m][1][i], x2 = s[m][2][i];
      float x3 = (r >= 1) ? -1e30f : s[m][3][i];
      float mx = fmaxf(fmaxf(x0, x1), fmaxf(x2, x3));
#pragma unroll
      for (int off = 1; off < 16; off <<= 1) mx = fmaxf(mx, __shfl_xor(mx, off, 64));
      float e0 = __expf(x0 - mx), e1 = __expf(x1 - mx), e2 = __expf(x2 - mx);
      float e3 = (r >= 1) ? 0.f : __expf(x3 - mx);
      float sum = e0 + e1 + e2 + e3;
#pragma unroll
      for (int off = 1; off < 16; off <<= 1) sum += __shfl_xor(sum, off, 64);
      float inv = 1.f / sum;
      int rowp = po + ((mt0 + m) * 16 + g * 4 + i) * 72;
      smem[rowp + r]       = f2bf(e0 * inv);
      smem[rowp + 16 + r]  = f2bf(e1 * inv);
      smem[rowp + 32 + r]  = f2bf(e2 * inv);
      smem[rowp + 48 + r]  = f2bf(e3 * inv);
    }
  }
  __syncthreads();   // V staged; P visible

  // ---- x_spa = P V ----
  f32x4 o[2][4];
#pragma unroll
  for (int m = 0; m < 2; ++m)
#pragma unroll
    for (int n = 0; n < 4; ++n) o[m][n] = fz;
#pragma unroll
  for (int kk = 0; kk < 2; ++kk) {
    u16x8 pa[2], vb[4];
#pragma unroll
    for (int m = 0; m < 2; ++m) pa[m] = *(const u16x8*)&smem[po + ((mt0 + m) * 16 + r) * 72 + kk * 32 + g * 8];
#pragma unroll
    for (int n = 0; n < 4; ++n) vb[n] = *(const u16x8*)&smem[vto + (n * 16 + r) * 72 + kk * 32 + g * 8];
#pragma unroll
    for (int m = 0; m < 2; ++m)
#pragma unroll
      for (int n = 0; n < 4; ++n) o[m][n] = mfma16(pa[m], vb[n], o[m][n]);
  }
  // write x_spa (bf16) over own P rows
#pragma unroll
  for (int m = 0; m < 2; ++m)
#pragma unroll
    for (int n = 0; n < 4; ++n)
#pragma unroll
      for (int i = 0; i < 4; ++i)
        smem[po + ((mt0 + m) * 16 + g * 4 + i) * 72 + n * 16 + r] = f2bf(o[m][n][i]);
  __syncthreads();

  // ---- depthwise conv (folded 7x7) + combine + write xo flat [t][256] ----
  {
    int c = lane;
    float in_f[49];
#pragma unroll
    for (int t2 = 0; t2 < 6; ++t2) {
      u16x8 raw = *(const u16x8*)&smem[vto + c * 72 + t2 * 8];
#pragma unroll
      for (int e = 0; e < 8; ++e) in_f[t2 * 8 + e] = bf2f(raw[e]);
    }
    in_f[48] = bf2f(smem[vto + c * 72 + 48]);
    float wreg[49];
    const float* wsrc = weffT + (size_t)(hc + c) * 52;
#pragma unroll
    for (int j = 0; j < 12; ++j) {
      float4 v = *(const float4*)(wsrc + j * 4);
      wreg[j * 4] = v.x; wreg[j * 4 + 1] = v.y; wreg[j * 4 + 2] = v.z; wreg[j * 4 + 3] = v.w;
    }
    wreg[48] = wsrc[48];
    size_t obase = tok0 * 256 + hc + c;
    if (hf == 0) conv_do<0, 25>(in_f, wreg, &smem[po], c, obase, xo);
    else         conv_do<25, 24>(in_f, wreg, &smem[po], c, obase, xo);
  }
}

// ---------------- K3: fused FFN  y = silu(xo@wfi^T)@wfo^T; out = LN(0.5y + xo) ----------------
// 128 tokens/block, 8 waves (wm 0..1, wn 0..3). h kept in LDS [128][264] (pad-8).
__global__ __launch_bounds__(512) void k_ffn(const u16* __restrict__ xo,
                                             const u16* __restrict__ wfi,
                                             const u16* __restrict__ wfo,
                                             const float* __restrict__ lng,
                                             const float* __restrict__ lnb,
                                             float* __restrict__ out){
  __shared__ __align__(16) u16 As[128 * 64];    // 16 KB (phase-1 A staging)
  __shared__ __align__(16) u16 Bs[256 * 64];    // 32 KB (B staging, both phases)
  __shared__ __align__(16) u16 hs[128 * 264];   // 67.6 KB hidden
  __shared__ float red1[4][128];
  __shared__ float red2[4][128];
  const int bid = blockIdx.x;
  const int bm = (bid & 7) * 98 + (bid >> 3);   // 784 = 8*98 XCD swizzle
  const int tid = threadIdx.x, lane = tid & 63, wid = tid >> 6;
  const int wm = wid >> 2, wn = wid & 3;
  const int r = lane & 15, g = lane >> 4;
  const int lr = lane >> 3;
  const int swz = ((lane & 7) ^ lr) * 16;
  const f32x4 fz = {0.f, 0.f, 0.f, 0.f};
  f32x4 acc[4][4];
#pragma unroll
  for (int m = 0; m < 4; ++m)
#pragma unroll
    for (int n = 0; n < 4; ++n) acc[m][n] = fz;

  const char* gA0 = (const char*)xo + (size_t)bm * 128 * 512;

  // ---- phase 1: h = silu(xo @ wfi^T) ----
  for (int kt = 0; kt < 4; ++kt) {
#pragma unroll
    for (int ri = 0; ri < 2; ++ri) {
      int chunk = ri * 8 + wid;
      int row = chunk * 8 + lr;
      g2l16(gA0 + (size_t)row * 512 + kt * 128 + swz, (char*)As + chunk * 1024);
    }
#pragma unroll
    for (int ri = 0; ri < 4; ++ri) {
      int chunk = ri * 8 + wid;
      int row = chunk * 8 + lr;
      g2l16((const char*)wfi + (size_t)row * 512 + kt * 128 + swz, (char*)Bs + chunk * 1024);
    }
    __syncthreads();
#pragma unroll
    for (int kk = 0; kk < 2; ++kk) {
      u16x8 af[4], bq[4];
#pragma unroll
      for (int m = 0; m < 4; ++m)
        af[m] = *(const u16x8*)&As[(wm * 64 + m * 16 + r) * 64 + (((kk * 4 + g) ^ (r & 7)) * 8)];
#pragma unroll
      for (int n = 0; n < 4; ++n)
        bq[n] = *(const u16x8*)&Bs[(wn * 64 + n * 16 + r) * 64 + (((kk * 4 + g) ^ (r & 7)) * 8)];
#pragma unroll
      for (int m = 0; m < 4; ++m)
#pragma unroll
        for (int n = 0; n < 4; ++n) acc[m][n] = mfma16(af[m], bq[n], acc[m][n]);
    }
    __syncthreads();
  }
  // SiLU -> hs
#pragma unroll
  for (int m = 0; m < 4; ++m)
#pragma unroll
    for (int i = 0; i < 4; ++i) {
      int row = wm * 64 + m * 16 + g * 4 + i;
#pragma unroll
      for (int n = 0; n < 4; ++n) {
        int col = wn * 64 + n * 16 + r;
        float v = acc[m][n][i];
        hs[row * 264 + col] = f2bf(v / (1.f + __expf(-v)));
      }
    }
  __syncthreads();

  // ---- phase 2: y = h @ wfo^T ----
#pragma unroll
  for (int m = 0; m < 4; ++m)
#pragma unroll
    for (int n = 0; n < 4; ++n) acc[m][n] = fz;
  for (int kt = 0; kt < 4; ++kt) {
#pragma unroll
    for (int ri = 0; ri < 4; ++ri) {
      int chunk = ri * 8 + wid;
      int row = chunk * 8 + lr;
      g2l16((const char*)wfo + (size_t)row * 512 + kt * 128 + swz, (char*)Bs + chunk * 1024);
    }
    __syncthreads();
#pragma unroll
    for (int kk = 0; kk < 2; ++kk) {
      u16x8 af[4], bq[4];
#pragma unroll
      for (int m = 0; m < 4; ++m)
        af[m] = *(const u16x8*)&hs[(wm * 64 + m * 16 + r) * 264 + kt * 64 + kk * 32 + g * 8];
#pragma unroll
      for (int n = 0; n < 4; ++n)
        bq[n] = *(const u16x8*)&Bs[(wn * 64 + n * 16 + r) * 64 + (((kk * 4 + g) ^ (r & 7)) * 8)];
#pragma unroll
      for (int m = 0; m < 4; ++m)
#pragma unroll
        for (int n = 0; n < 4; ++n) acc[m][n] = mfma16(af[m], bq[n], acc[m][n]);
    }
    __syncthreads();
  }

  // ---- epilogue: residual + LayerNorm + scatter ----
  float lg[4], lb[4];
#pragma unroll
  for (int n = 0; n < 4; ++n) {
    int col = wn * 64 + n * 16 + r;
    lg[n] = lng[col]; lb[n] = lnb[col];
  }
#pragma unroll
  for (int m = 0; m < 4; ++m)
#pragma unroll
    for (int i = 0; i < 4; ++i) {
      int t = bm * 128 + wm * 64 + m * 16 + g * 4 + i;
      const u16* xsrc = xo + (size_t)t * 256;
#pragma unroll
      for (int n = 0; n < 4; ++n) {
        int col = wn * 64 + n * 16 + r;
        acc[m][n][i] = 0.5f * acc[m][n][i] + bf2f(xsrc[col]);
      }
    }
#pragma unroll
  for (int m = 0; m < 4; ++m)
#pragma unroll
    for (int i = 0; i < 4; ++i) {
      float s1 = 0.f, s2 = 0.f;
#pragma unroll
      for (int n = 0; n < 4; ++n) { float v = acc[m][n][i]; s1 += v; s2 += v * v; }
#pragma unroll
      for (int off = 1; off < 16; off <<= 1) { s1 += __shfl_xor(s1, off, 64); s2 += __shfl_xor(s2, off, 64); }
      if (r == 0) {
        int rl = wm * 64 + m * 16 + g * 4 + i;
        red1[wn][rl] = s1; red2[wn][rl] = s2;
      }
    }
  __syncthreads();
#pragma unroll
  for (int m = 0; m < 4; ++m)
#pragma unroll
    for (int i = 0; i < 4; ++i) {
      int rl = wm * 64 + m * 16 + g * 4 + i;
      float S1 = red1[0][rl] + red1[1][rl] + red1[2][rl] + red1[3][rl];
      float S2 = red2[0][rl] + red2[1][rl] + red2[2][rl] + red2[3][rl];
      float mu = S1 * (1.f / 256.f);
      float var = S2 * (1.f / 256.f) - mu * mu;
      float rstd = rsqrtf(var + 1e-5f);
      int t = bm * 128 + rl;
      int b49 = t / 49, hw = t - b49 * 49;
      size_t ob = xrow_from(b49, hw);
#pragma unroll
      for (int n = 0; n < 4; ++n) {
        int col = wn * 64 + n * 16 + r;
        out[ob + col] = (acc[m][n][i] - mu) * rstd * lg[n] + lb[n];
      }
    }
}

// ---------------- launch ----------------
extern "C" void kernel_launch(void* const* d_in, const int* in_sizes, int n_in,
                              void* d_out, int out_size, void* d_ws, size_t ws_size,
                              hipStream_t stream) {
  (void)in_sizes; (void)n_in; (void)out_size; (void)ws_size;
  const float* x     = (const float*)d_in[0];
  const float* qkvw  = (const float*)d_in[1];
  const float* qkvb  = (const float*)d_in[2];
  const float* c3    = (const float*)d_in[3];
  const float* c5    = (const float*)d_in[4];
  const float* c7    = (const float*)d_in[5];
  const float* fin   = (const float*)d_in[6];
  const float* fout  = (const float*)d_in[7];
  const float* lng   = (const float*)d_in[8];
  const float* lnb   = (const float*)d_in[9];
  float* out = (float*)d_out;
  char* ws = (char*)d_ws;

  u16*   qbuf  = (u16*)(ws);                      // 51380224 B
  u16*   kbuf  = (u16*)(ws + 51380224);           // 51380224 B ; reused as xo by K2+
  u16*   vmb   = (u16*)(ws + 102760448);          // 51380224 B
  u16*   wq    = (u16*)(ws + 154140672);          // 393216 B
  u16*   wfi   = (u16*)(ws + 154533888);          // 131072 B
  u16*   wfo   = (u16*)(ws + 154664960);          // 131072 B
  float* weffT = (float*)(ws + 154796032);        // 53248 B  [256ch][52]
  u16*   xbf   = (u16*)d_out;                     // scratch: 51MB bf16 x, dead before k_ffn

  k_prep<<<dim3(1329), dim3(256), 0, stream>>>(qkvw, c3, c5, c7, fin, fout, wq, wfi, wfo, weffT);
  k_xbf<<<dim3(25088), dim3(256), 0, stream>>>(x, xbf);
  k_qkv<<<dim3(4704), dim3(256), 0, stream>>>(xbf, wq, qkvb, qbuf, kbuf, vmb);
  k_attn<<<dim3(4096), dim3(256), 0, stream>>>(qbuf, kbuf, vmb, weffT, kbuf /*xo alias*/);
  k_ffn<<<dim3(784), dim3(512), 0, stream>>>(kbuf /*xo*/, wfi, wfo, lng, lnb, out);
}

// Round 12
// 260.142 us; speedup vs baseline: 1.0331x; 1.0331x over previous
//
#include <hip/hip_runtime.h>

typedef unsigned short u16;
typedef unsigned short u16x8 __attribute__((ext_vector_type(8)));
typedef unsigned short u16x4 __attribute__((ext_vector_type(4)));
typedef unsigned int   u32x2 __attribute__((ext_vector_type(2)));
typedef short          s16x8 __attribute__((ext_vector_type(8)));
typedef float          f32x4 __attribute__((ext_vector_type(4)));

#define DEV static __device__ __forceinline__

DEV float bf2f(u16 u){ unsigned int v = ((unsigned int)u) << 16; return __builtin_bit_cast(float, v); }
DEV u16 f2bf(float f){
  unsigned int u = __builtin_bit_cast(unsigned int, f);
  u += 0x7fffu + ((u >> 16) & 1u);
  return (u16)(u >> 16);
}

DEV f32x4 mfma16(u16x8 a, u16x8 b, f32x4 c){
  return __builtin_amdgcn_mfma_f32_16x16x32_bf16(
      __builtin_bit_cast(s16x8, a), __builtin_bit_cast(s16x8, b), c, 0, 0, 0);
}

// async global->LDS, 16B per lane; lds dest must be wave-uniform base
DEV void g2l16(const void* g, void* l){
  __builtin_amdgcn_global_load_lds((const __attribute__((address_space(1))) void*)g,
                                   (__attribute__((address_space(3))) void*)l, 16, 0, 0);
}

// token t (windowed order) -> float offset of its 256-channel row in x / out [B,56,56,256]
DEV size_t xrow_from(int b, int hw){
  int h1 = hw / 7, w1 = hw - h1 * 7;
  return ((size_t)(((b >> 6) * 56 + h1 * 8 + ((b >> 3) & 7)) * 56 + (w1 * 8 + (b & 7)))) << 8;
}
DEV size_t xrow_off(int t){ int b = t / 49; return xrow_from(b, t - b * 49); }

// ---------------- K0: x->bf16 windowed + weight prep (merged) ----------------
__global__ __launch_bounds__(256) void k_pre(const float* __restrict__ x, u16* __restrict__ xbf,
                                             const float* __restrict__ qkvw,
                                             const float* __restrict__ c3,
                                             const float* __restrict__ c5,
                                             const float* __restrict__ c7,
                                             const float* __restrict__ fin,
                                             const float* __restrict__ fout,
                                             u16* __restrict__ wq, u16* __restrict__ wfi,
                                             u16* __restrict__ wfo, float* __restrict__ weffT){
  int tid = threadIdx.x;
  if (blockIdx.x < 25088) {
    int tok = blockIdx.x * 4 + (tid >> 6);
    int c4 = (tid & 63) * 4;
    float4 v = *(const float4*)(x + xrow_off(tok) + c4);
    u16x4 o; o[0] = f2bf(v.x); o[1] = f2bf(v.y); o[2] = f2bf(v.z); o[3] = f2bf(v.w);
    *(u16x4*)&xbf[(size_t)tok * 256 + c4] = o;
    return;
  }
  int id = (blockIdx.x - 25088) * 256 + tid;
  if (id < 196608) { wq[id] = f2bf(qkvw[id]); return; }
  id -= 196608;
  if (id < 65536) { wfi[id] = f2bf(fin[id]); return; }
  id -= 65536;
  if (id < 65536) { wfo[id] = f2bf(fout[id]); return; }
  id -= 65536;
  if (id < 12544) {
    int c = id / 49, t = id - c * 49;
    int di = t / 7 - 3, dj = t % 7 - 3;
    float s = c7[c * 49 + t];
    if (di >= -2 && di <= 2 && dj >= -2 && dj <= 2) s += c5[c * 25 + (di + 2) * 5 + (dj + 2)];
    if (di >= -1 && di <= 1 && dj >= -1 && dj <= 1) s += c3[c * 9 + (di + 1) * 3 + (dj + 1)];
    weffT[c * 52 + t] = 0.05f * s;   // BETA*0.25 folded; [channel][49 taps], stride 52
  }
}

// ---------------- K1: QKV GEMM  M=100352 N=768 K=256 (flat [t][256] epilogue) ----------------
__global__ __launch_bounds__(256) void k_qkv(const u16* __restrict__ xbf,
                                             const u16* __restrict__ wq,
                                             const float* __restrict__ qkvb,
                                             u16* __restrict__ qb, u16* __restrict__ kb,
                                             u16* __restrict__ vmb){
  __shared__ __align__(16) u16 As[128 * 64];
  __shared__ __align__(16) u16 Bs[128 * 64];
  const int bid = blockIdx.x;
  const int lin = (bid & 7) * 588 + (bid >> 3);  // XCD-chunk swizzle (4704 = 8*588)
  const int bm = lin / 6, bn = lin - bm * 6;
  const int tid = threadIdx.x, lane = tid & 63, wid = tid >> 6;
  const int wm = wid >> 1, wn = wid & 1;
  const int r = lane & 15, g = lane >> 4;
  const int lr = lane >> 3;
  const int swz = ((lane & 7) ^ lr) * 16;        // pre-swizzled global source block
  const f32x4 fz = {0.f, 0.f, 0.f, 0.f};
  f32x4 acc[4][4];
#pragma unroll
  for (int m = 0; m < 4; ++m)
#pragma unroll
    for (int n = 0; n < 4; ++n) acc[m][n] = fz;

  const char* gA0 = (const char*)xbf + (size_t)bm * 128 * 512;
  const char* gB0 = (const char*)wq  + (size_t)bn * 128 * 512;

  for (int kt = 0; kt < 4; ++kt) {
#pragma unroll
    for (int ri = 0; ri < 4; ++ri) {
      int chunk = ri * 4 + wid;
      int row = chunk * 8 + lr;
      g2l16(gA0 + (size_t)row * 512 + kt * 128 + swz, (char*)As + chunk * 1024);
      g2l16(gB0 + (size_t)row * 512 + kt * 128 + swz, (char*)Bs + chunk * 1024);
    }
    __syncthreads();
#pragma unroll
    for (int kk = 0; kk < 2; ++kk) {
      u16x8 af[4], bq[4];
#pragma unroll
      for (int m = 0; m < 4; ++m)
        af[m] = *(const u16x8*)&As[(wm * 64 + m * 16 + r) * 64 + (((kk * 4 + g) ^ (r & 7)) * 8)];
#pragma unroll
      for (int n = 0; n < 4; ++n)
        bq[n] = *(const u16x8*)&Bs[(wn * 64 + n * 16 + r) * 64 + (((kk * 4 + g) ^ (r & 7)) * 8)];
#pragma unroll
      for (int m = 0; m < 4; ++m)
#pragma unroll
        for (int n = 0; n < 4; ++n) acc[m][n] = mfma16(af[m], bq[n], acc[m][n]);
    }
    __syncthreads();
  }

  // epilogue: flat [t][256] stores, no divisions
  const int sec = bn >> 1;                       // 0=q 1=k 2=v
  const int cb = (bn & 1) * 128 + wn * 64;       // section-local col base
  u16* const outp = (sec == 0) ? qb : (sec == 1) ? kb : vmb;
  float bias[4];
#pragma unroll
  for (int n = 0; n < 4; ++n) bias[n] = qkvb[sec * 256 + cb + n * 16 + r];
#pragma unroll
  for (int m = 0; m < 4; ++m) {
#pragma unroll
    for (int i = 0; i < 4; ++i) {
      int t = bm * 128 + wm * 64 + m * 16 + g * 4 + i;
      u16* dst = outp + (size_t)t * 256 + cb;
      if (sec == 0) {
#pragma unroll
        for (int n = 0; n < 4; ++n) dst[n * 16 + r] = f2bf((acc[m][n][i] + bias[n]) * 0.125f);
      } else if (sec == 1) {
#pragma unroll
        for (int n = 0; n < 4; ++n) dst[n * 16 + r] = f2bf(acc[m][n][i] + bias[n]);
      } else {
        const u16* xsrc = xbf + (size_t)t * 256 + cb;
#pragma unroll
        for (int n = 0; n < 4; ++n)
          dst[n * 16 + r] = f2bf(0.1f * (acc[m][n][i] + bias[n]) + bf2f(xsrc[n * 16 + r]));
      }
    }
  }
}

// ---------------- K2: attention + conv + combine (split V-gather; flat xo [t][256]) ----------------
template<int HW0, int NPIX>
DEV void conv_do(const float (&in_f)[49], const float (&wreg)[49], const u16* xs,
                 int c, size_t obase, u16* __restrict__ xo){
#pragma unroll
  for (int p = 0; p < NPIX; ++p) {
    const int hw = HW0 + p;
    const int i0 = hw / 7, j0 = hw % 7;
    float a = 0.f;
#pragma unroll
    for (int di = -3; di <= 3; ++di) {
      const int ii = i0 + di;
      if (ii < 0 || ii > 6) continue;
#pragma unroll
      for (int dj = -3; dj <= 3; ++dj) {
        const int jj = j0 + dj;
        if (jj < 0 || jj > 6) continue;
        a += in_f[ii * 7 + jj] * wreg[(di + 3) * 7 + (dj + 3)];
      }
    }
    float xsv = bf2f(xs[hw * 72 + c]);
    float outv = in_f[hw] + 0.05f * xsv + a;
    xo[obase + (size_t)hw * 256] = f2bf(outv);
  }
}

__global__ __launch_bounds__(256) void k_attn(const u16* __restrict__ qb,
                                              const u16* __restrict__ kb,
                                              const u16* __restrict__ vmb,
                                              const float* __restrict__ weffT,
                                              u16* __restrict__ xo){
  __shared__ __align__(16) u16 smem[18432];   // per head: Vt 64*72 @hl*9216, P 64*72 @+4608
  const int bx = blockIdx.x;
  const int b = bx >> 1, hp = bx & 1;
  const int tid = threadIdx.x, lane = tid & 63, wid = tid >> 6;
  const int hl = wid >> 1, hf = wid & 1;      // head_local, half
  const int hg = hp * 2 + hl;                 // global head
  const int vto = hl * 9216, po = hl * 9216 + 4608;
  const int r = lane & 15, g = lane >> 4;
  const size_t tok0 = (size_t)b * 49;         // first token of window
  const int hc = hg * 64;                     // head channel base

  // ---- stage v transposed vT[d][key]: split across the two hf-waves ----
  {
    int c = lane;
    if (hf == 0) {
      u16 pix[24];
#pragma unroll
      for (int hw = 0; hw < 24; ++hw) pix[hw] = vmb[(tok0 + hw) * 256 + hc + c];
#pragma unroll
      for (int t2 = 0; t2 < 6; ++t2) {
        u32x2 w;
        w[0] = (unsigned)pix[4 * t2] | ((unsigned)pix[4 * t2 + 1] << 16);
        w[1] = (unsigned)pix[4 * t2 + 2] | ((unsigned)pix[4 * t2 + 3] << 16);
        *(u32x2*)&smem[vto + c * 72 + 4 * t2] = w;
      }
    } else {
      u16 pix[25];
#pragma unroll
      for (int hw = 0; hw < 25; ++hw) pix[hw] = vmb[(tok0 + 24 + hw) * 256 + hc + c];
#pragma unroll
      for (int t2 = 0; t2 < 6; ++t2) {
        u32x2 w;
        w[0] = (unsigned)pix[4 * t2] | ((unsigned)pix[4 * t2 + 1] << 16);
        w[1] = (unsigned)pix[4 * t2 + 2] | ((unsigned)pix[4 * t2 + 3] << 16);
        *(u32x2*)&smem[vto + c * 72 + 24 + 4 * t2] = w;
      }
      u32x2 wl; wl[0] = (unsigned)pix[24]; wl[1] = 0u;
      *(u32x2*)&smem[vto + c * 72 + 48] = wl;
      u32x2 z; z[0] = 0u; z[1] = 0u;
      *(u32x2*)&smem[vto + c * 72 + 52] = z;
      *(u32x2*)&smem[vto + c * 72 + 56] = z;
      *(u32x2*)&smem[vto + c * 72 + 60] = z;
    }
  }

  // ---- S = Q K^T, fragments loaded directly global->VGPR ----
  const int mt0 = hf * 2;
  const f32x4 fz = {0.f, 0.f, 0.f, 0.f};
  f32x4 s[2][4];
#pragma unroll
  for (int m = 0; m < 2; ++m)
#pragma unroll
    for (int n = 0; n < 4; ++n) s[m][n] = fz;
  u16x8 aq[2][2], bk[4][2];
#pragma unroll
  for (int m = 0; m < 2; ++m) {
    int qrow = (mt0 + m) * 16 + r; if (qrow > 48) qrow = 48;   // junk rows -> dup, never read
    const u16* src = qb + (tok0 + qrow) * 256 + hc;
    aq[m][0] = *(const u16x8*)(src + g * 8);
    aq[m][1] = *(const u16x8*)(src + 32 + g * 8);
  }
#pragma unroll
  for (int n = 0; n < 4; ++n) {
    int krow = n * 16 + r; if (krow > 48) krow = 0;            // junk keys masked below
    const u16* src = kb + (tok0 + krow) * 256 + hc;
    bk[n][0] = *(const u16x8*)(src + g * 8);
    bk[n][1] = *(const u16x8*)(src + 32 + g * 8);
  }
#pragma unroll
  for (int kk = 0; kk < 2; ++kk)
#pragma unroll
    for (int m = 0; m < 2; ++m)
#pragma unroll
      for (int n = 0; n < 4; ++n) s[m][n] = mfma16(aq[m][kk], bk[n][kk], s[m][n]);

  // ---- softmax (rows = queries), mask cols >= 49, write P bf16 ----
#pragma unroll
  for (int m = 0; m < 2; ++m) {
#pragma unroll
    for (int i = 0; i < 4; ++i) {
      float x0 = s[m][0][i], x1 = s[m][1][i], x2 = s[m][2][i];
      float x3 = (r >= 1) ? -1e30f : s[m][3][i];
      float mx = fmaxf(fmaxf(x0, x1), fmaxf(x2, x3));
#pragma unroll
      for (int off = 1; off < 16; off <<= 1) mx = fmaxf(mx, __shfl_xor(mx, off, 64));
      float e0 = __expf(x0 - mx), e1 = __expf(x1 - mx), e2 = __expf(x2 - mx);
      float e3 = (r >= 1) ? 0.f : __expf(x3 - mx);
      float sum = e0 + e1 + e2 + e3;
#pragma unroll
      for (int off = 1; off < 16; off <<= 1) sum += __shfl_xor(sum, off, 64);
      float inv = 1.f / sum;
      int rowp = po + ((mt0 + m) * 16 + g * 4 + i) * 72;
      smem[rowp + r]       = f2bf(e0 * inv);
      smem[rowp + 16 + r]  = f2bf(e1 * inv);
      smem[rowp + 32 + r]  = f2bf(e2 * inv);
      smem[rowp + 48 + r]  = f2bf(e3 * inv);
    }
  }
  __syncthreads();   // V staged; P visible

  // ---- x_spa = P V ----
  f32x4 o[2][4];
#pragma unroll
  for (int m = 0; m < 2; ++m)
#pragma unroll
    for (int n = 0; n < 4; ++n) o[m][n] = fz;
#pragma unroll
  for (int kk = 0; kk < 2; ++kk) {
    u16x8 pa[2], vb[4];
#pragma unroll
    for (int m = 0; m < 2; ++m) pa[m] = *(const u16x8*)&smem[po + ((mt0 + m) * 16 + r) * 72 + kk * 32 + g * 8];
#pragma unroll
    for (int n = 0; n < 4; ++n) vb[n] = *(const u16x8*)&smem[vto + (n * 16 + r) * 72 + kk * 32 + g * 8];
#pragma unroll
    for (int m = 0; m < 2; ++m)
#pragma unroll
      for (int n = 0; n < 4; ++n) o[m][n] = mfma16(pa[m], vb[n], o[m][n]);
  }
  // write x_spa (bf16) over own P rows
#pragma unroll
  for (int m = 0; m < 2; ++m)
#pragma unroll
    for (int n = 0; n < 4; ++n)
#pragma unroll
      for (int i = 0; i < 4; ++i)
        smem[po + ((mt0 + m) * 16 + g * 4 + i) * 72 + n * 16 + r] = f2bf(o[m][n][i]);
  __syncthreads();

  // ---- depthwise conv (folded 7x7) + combine + write xo flat [t][256] ----
  {
    int c = lane;
    float in_f[49];
#pragma unroll
    for (int t2 = 0; t2 < 6; ++t2) {
      u16x8 raw = *(const u16x8*)&smem[vto + c * 72 + t2 * 8];
#pragma unroll
      for (int e = 0; e < 8; ++e) in_f[t2 * 8 + e] = bf2f(raw[e]);
    }
    in_f[48] = bf2f(smem[vto + c * 72 + 48]);
    float wreg[49];
    const float* wsrc = weffT + (size_t)(hc + c) * 52;
#pragma unroll
    for (int j = 0; j < 12; ++j) {
      float4 v = *(const float4*)(wsrc + j * 4);
      wreg[j * 4] = v.x; wreg[j * 4 + 1] = v.y; wreg[j * 4 + 2] = v.z; wreg[j * 4 + 3] = v.w;
    }
    wreg[48] = wsrc[48];
    size_t obase = tok0 * 256 + hc + c;
    if (hf == 0) conv_do<0, 25>(in_f, wreg, &smem[po], c, obase, xo);
    else         conv_do<25, 24>(in_f, wreg, &smem[po], c, obase, xo);
  }
}

// ---------------- K3: FFN-in + SiLU  M=100352 N=256 K=256 (flat xo, no divisions) ----------------
__global__ __launch_bounds__(256) void k_ffn1(const u16* __restrict__ xo,
                                              const u16* __restrict__ wfi,
                                              u16* __restrict__ h){
  __shared__ __align__(16) u16 As[128 * 64];
  __shared__ __align__(16) u16 Bs[128 * 64];
  const int bid = blockIdx.x;
  const int lin = (bid & 7) * 196 + (bid >> 3);  // 1568 = 8*196
  const int bm = lin >> 1, bn = lin & 1;
  const int tid = threadIdx.x, lane = tid & 63, wid = tid >> 6;
  const int wm = wid >> 1, wn = wid & 1;
  const int r = lane & 15, g = lane >> 4;
  const int lr = lane >> 3;
  const int swz = ((lane & 7) ^ lr) * 16;
  const f32x4 fz = {0.f, 0.f, 0.f, 0.f};
  f32x4 acc[4][4];
#pragma unroll
  for (int m = 0; m < 4; ++m)
#pragma unroll
    for (int n = 0; n < 4; ++n) acc[m][n] = fz;

  const char* gA0 = (const char*)xo + (size_t)bm * 128 * 512;
  const char* gB0 = (const char*)wfi + (size_t)bn * 128 * 512;

  for (int kt = 0; kt < 4; ++kt) {
#pragma unroll
    for (int ri = 0; ri < 4; ++ri) {
      int chunk = ri * 4 + wid;
      int row = chunk * 8 + lr;
      g2l16(gA0 + (size_t)row * 512 + kt * 128 + swz, (char*)As + chunk * 1024);
      g2l16(gB0 + (size_t)row * 512 + kt * 128 + swz, (char*)Bs + chunk * 1024);
    }
    __syncthreads();
#pragma unroll
    for (int kk = 0; kk < 2; ++kk) {
      u16x8 af[4], bq[4];
#pragma unroll
      for (int m = 0; m < 4; ++m)
        af[m] = *(const u16x8*)&As[(wm * 64 + m * 16 + r) * 64 + (((kk * 4 + g) ^ (r & 7)) * 8)];
#pragma unroll
      for (int n = 0; n < 4; ++n)
        bq[n] = *(const u16x8*)&Bs[(wn * 64 + n * 16 + r) * 64 + (((kk * 4 + g) ^ (r & 7)) * 8)];
#pragma unroll
      for (int m = 0; m < 4; ++m)
#pragma unroll
        for (int n = 0; n < 4; ++n) acc[m][n] = mfma16(af[m], bq[n], acc[m][n]);
    }
    __syncthreads();
  }
#pragma unroll
  for (int m = 0; m < 4; ++m)
#pragma unroll
    for (int i = 0; i < 4; ++i) {
      int t = bm * 128 + wm * 64 + m * 16 + g * 4 + i;
      u16* dst = h + (size_t)t * 256 + bn * 128 + wn * 64;
#pragma unroll
      for (int n = 0; n < 4; ++n) {
        float v = acc[m][n][i];
        float sg = v / (1.f + __expf(-v));
        dst[n * 16 + r] = f2bf(sg);
      }
    }
}

// ---------------- K4: FFN-out + residual + LayerNorm + scatter (flat xo) ----------------
__global__ __launch_bounds__(512) void k_ffn2(const u16* __restrict__ h,
                                              const u16* __restrict__ wfo,
                                              const u16* __restrict__ xo,
                                              const float* __restrict__ lng,
                                              const float* __restrict__ lnb,
                                              float* __restrict__ out){
  __shared__ __align__(16) u16 As[128 * 64];
  __shared__ __align__(16) u16 Bs[256 * 64];
  __shared__ float red1[4][128];
  __shared__ float red2[4][128];
  const int bm = blockIdx.x;
  const int tid = threadIdx.x, lane = tid & 63, wid = tid >> 6;
  const int wm = wid >> 2, wn = wid & 3;
  const int r = lane & 15, g = lane >> 4;
  const int lr = lane >> 3;
  const int swz = ((lane & 7) ^ lr) * 16;
  const f32x4 fz = {0.f, 0.f, 0.f, 0.f};
  f32x4 acc[4][4];
#pragma unroll
  for (int m = 0; m < 4; ++m)
#pragma unroll
    for (int n = 0; n < 4; ++n) acc[m][n] = fz;

  for (int kt = 0; kt < 4; ++kt) {
#pragma unroll
    for (int ri = 0; ri < 2; ++ri) {
      int chunk = ri * 8 + wid;
      int row = chunk * 8 + lr;
      g2l16((const char*)h + (size_t)(bm * 128 + row) * 512 + kt * 128 + swz, (char*)As + chunk * 1024);
    }
#pragma unroll
    for (int ri = 0; ri < 4; ++ri) {
      int chunk = ri * 8 + wid;
      int row = chunk * 8 + lr;
      g2l16((const char*)wfo + (size_t)row * 512 + kt * 128 + swz, (char*)Bs + chunk * 1024);
    }
    __syncthreads();
#pragma unroll
    for (int kk = 0; kk < 2; ++kk) {
      u16x8 af[4], bq[4];
#pragma unroll
      for (int m = 0; m < 4; ++m)
        af[m] = *(const u16x8*)&As[(wm * 64 + m * 16 + r) * 64 + (((kk * 4 + g) ^ (r & 7)) * 8)];
#pragma unroll
      for (int n = 0; n < 4; ++n)
        bq[n] = *(const u16x8*)&Bs[(wn * 64 + n * 16 + r) * 64 + (((kk * 4 + g) ^ (r & 7)) * 8)];
#pragma unroll
      for (int m = 0; m < 4; ++m)
#pragma unroll
        for (int n = 0; n < 4; ++n) acc[m][n] = mfma16(af[m], bq[n], acc[m][n]);
    }
    __syncthreads();
  }

  float lg[4], lb[4];
#pragma unroll
  for (int n = 0; n < 4; ++n) {
    int col = wn * 64 + n * 16 + r;
    lg[n] = lng[col]; lb[n] = lnb[col];
  }
  // residual: val = 0.5*y + xo (flat [t][256])
#pragma unroll
  for (int m = 0; m < 4; ++m)
#pragma unroll
    for (int i = 0; i < 4; ++i) {
      int t = bm * 128 + wm * 64 + m * 16 + g * 4 + i;
      const u16* xsrc = xo + (size_t)t * 256;
#pragma unroll
      for (int n = 0; n < 4; ++n) {
        int col = wn * 64 + n * 16 + r;
        acc[m][n][i] = 0.5f * acc[m][n][i] + bf2f(xsrc[col]);
      }
    }
  // per-row partial sums over this wave's 64 cols
#pragma unroll
  for (int m = 0; m < 4; ++m)
#pragma unroll
    for (int i = 0; i < 4; ++i) {
      float s1 = 0.f, s2 = 0.f;
#pragma unroll
      for (int n = 0; n < 4; ++n) { float v = acc[m][n][i]; s1 += v; s2 += v * v; }
#pragma unroll
      for (int off = 1; off < 16; off <<= 1) { s1 += __shfl_xor(s1, off, 64); s2 += __shfl_xor(s2, off, 64); }
      if (r == 0) {
        int rl = wm * 64 + m * 16 + g * 4 + i;
        red1[wn][rl] = s1; red2[wn][rl] = s2;
      }
    }
  __syncthreads();
#pragma unroll
  for (int m = 0; m < 4; ++m)
#pragma unroll
    for (int i = 0; i < 4; ++i) {
      int rl = wm * 64 + m * 16 + g * 4 + i;
      float S1 = red1[0][rl] + red1[1][rl] + red1[2][rl] + red1[3][rl];
      float S2 = red2[0][rl] + red2[1][rl] + red2[2][rl] + red2[3][rl];
      float mu = S1 * (1.f / 256.f);
      float var = S2 * (1.f / 256.f) - mu * mu;
      float rstd = rsqrtf(var + 1e-5f);
      int t = bm * 128 + rl;
      int b49 = t / 49, hw = t - b49 * 49;
      size_t ob = xrow_from(b49, hw);
#pragma unroll
      for (int n = 0; n < 4; ++n) {
        int col = wn * 64 + n * 16 + r;
        out[ob + col] = (acc[m][n][i] - mu) * rstd * lg[n] + lb[n];
      }
    }
}

// ---------------- launch ----------------
extern "C" void kernel_launch(void* const* d_in, const int* in_sizes, int n_in,
                              void* d_out, int out_size, void* d_ws, size_t ws_size,
                              hipStream_t stream) {
  (void)in_sizes; (void)n_in; (void)out_size; (void)ws_size;
  const float* x     = (const float*)d_in[0];
  const float* qkvw  = (const float*)d_in[1];
  const float* qkvb  = (const float*)d_in[2];
  const float* c3    = (const float*)d_in[3];
  const float* c5    = (const float*)d_in[4];
  const float* c7    = (const float*)d_in[5];
  const float* fin   = (const float*)d_in[6];
  const float* fout  = (const float*)d_in[7];
  const float* lng   = (const float*)d_in[8];
  const float* lnb   = (const float*)d_in[9];
  float* out = (float*)d_out;
  char* ws = (char*)d_ws;

  u16*   qbuf  = (u16*)(ws);                      // 51380224 B ; reused as h by K3/K4
  u16*   kbuf  = (u16*)(ws + 51380224);           // 51380224 B ; reused as xo by K2+
  u16*   vmb   = (u16*)(ws + 102760448);          // 51380224 B
  u16*   wq    = (u16*)(ws + 154140672);          // 393216 B
  u16*   wfi   = (u16*)(ws + 154533888);          // 131072 B
  u16*   wfo   = (u16*)(ws + 154664960);          // 131072 B
  float* weffT = (float*)(ws + 154796032);        // 53248 B  [256ch][52]
  u16*   xbf   = (u16*)d_out;                     // scratch: 51MB bf16 x, dead before k_ffn2

  k_pre<<<dim3(26417), dim3(256), 0, stream>>>(x, xbf, qkvw, c3, c5, c7, fin, fout, wq, wfi, wfo, weffT);
  k_qkv<<<dim3(4704), dim3(256), 0, stream>>>(xbf, wq, qkvb, qbuf, kbuf, vmb);
  k_attn<<<dim3(4096), dim3(256), 0, stream>>>(qbuf, kbuf, vmb, weffT, kbuf /*xo alias*/);
  k_ffn1<<<dim3(1568), dim3(256), 0, stream>>>(kbuf /*xo*/, wfi, qbuf /*h alias*/);
  k_ffn2<<<dim3(784), dim3(512), 0, stream>>>(qbuf /*h*/, wfo, kbuf /*xo*/, lng, lnb, out);
}

// Round 13
// 257.198 us; speedup vs baseline: 1.0449x; 1.0114x over previous
//
#include <hip/hip_runtime.h>

typedef unsigned short u16;
typedef unsigned char  u8;
typedef unsigned short u16x8 __attribute__((ext_vector_type(8)));
typedef unsigned short u16x4 __attribute__((ext_vector_type(4)));
typedef unsigned int   u32x2 __attribute__((ext_vector_type(2)));
typedef short          s16x8 __attribute__((ext_vector_type(8)));
typedef float          f32x4 __attribute__((ext_vector_type(4)));

#define DEV static __device__ __forceinline__

DEV float bf2f(u16 u){ unsigned int v = ((unsigned int)u) << 16; return __builtin_bit_cast(float, v); }
DEV u16 f2bf(float f){
  unsigned int u = __builtin_bit_cast(unsigned int, f);
  u += 0x7fffu + ((u >> 16) & 1u);
  return (u16)(u >> 16);
}
DEV u8 f2fp8(float f){
  int p = __builtin_amdgcn_cvt_pk_fp8_f32(f, f, 0, false);
  return (u8)(p & 0xff);
}

DEV f32x4 mfma16(u16x8 a, u16x8 b, f32x4 c){
  return __builtin_amdgcn_mfma_f32_16x16x32_bf16(
      __builtin_bit_cast(s16x8, a), __builtin_bit_cast(s16x8, b), c, 0, 0, 0);
}
DEV f32x4 mfma_fp8(long a, long b, f32x4 c){
  return __builtin_amdgcn_mfma_f32_16x16x32_fp8_fp8(a, b, c, 0, 0, 0);
}

// async global->LDS, 16B per lane; lds dest must be wave-uniform base
DEV void g2l16(const void* g, void* l){
  __builtin_amdgcn_global_load_lds((const __attribute__((address_space(1))) void*)g,
                                   (__attribute__((address_space(3))) void*)l, 16, 0, 0);
}

// token t (windowed order) -> float offset of its 256-channel row in x / out [B,56,56,256]
DEV size_t xrow_from(int b, int hw){
  int h1 = hw / 7, w1 = hw - h1 * 7;
  return ((size_t)(((b >> 6) * 56 + h1 * 8 + ((b >> 3) & 7)) * 56 + (w1 * 8 + (b & 7)))) << 8;
}
DEV size_t xrow_off(int t){ int b = t / 49; return xrow_from(b, t - b * 49); }

// ---------------- K0: x->bf16 windowed + weight prep (merged) ----------------
__global__ __launch_bounds__(256) void k_pre(const float* __restrict__ x, u16* __restrict__ xbf,
                                             const float* __restrict__ qkvw,
                                             const float* __restrict__ c3,
                                             const float* __restrict__ c5,
                                             const float* __restrict__ c7,
                                             const float* __restrict__ fin,
                                             const float* __restrict__ fout,
                                             u16* __restrict__ wq, u16* __restrict__ wfi,
                                             u16* __restrict__ wfo, float* __restrict__ weffT){
  int tid = threadIdx.x;
  if (blockIdx.x < 25088) {
    int tok = blockIdx.x * 4 + (tid >> 6);
    int c4 = (tid & 63) * 4;
    float4 v = *(const float4*)(x + xrow_off(tok) + c4);
    u16x4 o; o[0] = f2bf(v.x); o[1] = f2bf(v.y); o[2] = f2bf(v.z); o[3] = f2bf(v.w);
    *(u16x4*)&xbf[(size_t)tok * 256 + c4] = o;
    return;
  }
  int id = (blockIdx.x - 25088) * 256 + tid;
  if (id < 196608) { wq[id] = f2bf(qkvw[id]); return; }
  id -= 196608;
  if (id < 65536) { wfi[id] = f2bf(fin[id]); return; }
  id -= 65536;
  if (id < 65536) { wfo[id] = f2bf(fout[id]); return; }
  id -= 65536;
  if (id < 12544) {
    int c = id / 49, t = id - c * 49;
    int di = t / 7 - 3, dj = t % 7 - 3;
    float s = c7[c * 49 + t];
    if (di >= -2 && di <= 2 && dj >= -2 && dj <= 2) s += c5[c * 25 + (di + 2) * 5 + (dj + 2)];
    if (di >= -1 && di <= 1 && dj >= -1 && dj <= 1) s += c3[c * 9 + (di + 1) * 3 + (dj + 1)];
    weffT[c * 52 + t] = 0.05f * s;   // BETA*0.25 folded; [channel][49 taps], stride 52
  }
}

// ---------------- K1: QKV GEMM  M=100352 N=768 K=256 (q/k -> fp8, v -> bf16) ----------------
__global__ __launch_bounds__(256) void k_qkv(const u16* __restrict__ xbf,
                                             const u16* __restrict__ wq,
                                             const float* __restrict__ qkvb,
                                             u8* __restrict__ qb8, u8* __restrict__ kb8,
                                             u16* __restrict__ vmb){
  __shared__ __align__(16) u16 As[128 * 64];
  __shared__ __align__(16) u16 Bs[128 * 64];
  const int bid = blockIdx.x;
  const int lin = (bid & 7) * 588 + (bid >> 3);  // XCD-chunk swizzle (4704 = 8*588)
  const int bm = lin / 6, bn = lin - bm * 6;
  const int tid = threadIdx.x, lane = tid & 63, wid = tid >> 6;
  const int wm = wid >> 1, wn = wid & 1;
  const int r = lane & 15, g = lane >> 4;
  const int lr = lane >> 3;
  const int swz = ((lane & 7) ^ lr) * 16;        // pre-swizzled global source block
  const f32x4 fz = {0.f, 0.f, 0.f, 0.f};
  f32x4 acc[4][4];
#pragma unroll
  for (int m = 0; m < 4; ++m)
#pragma unroll
    for (int n = 0; n < 4; ++n) acc[m][n] = fz;

  const char* gA0 = (const char*)xbf + (size_t)bm * 128 * 512;
  const char* gB0 = (const char*)wq  + (size_t)bn * 128 * 512;

  for (int kt = 0; kt < 4; ++kt) {
#pragma unroll
    for (int ri = 0; ri < 4; ++ri) {
      int chunk = ri * 4 + wid;
      int row = chunk * 8 + lr;
      g2l16(gA0 + (size_t)row * 512 + kt * 128 + swz, (char*)As + chunk * 1024);
      g2l16(gB0 + (size_t)row * 512 + kt * 128 + swz, (char*)Bs + chunk * 1024);
    }
    __syncthreads();
#pragma unroll
    for (int kk = 0; kk < 2; ++kk) {
      u16x8 af[4], bq[4];
#pragma unroll
      for (int m = 0; m < 4; ++m)
        af[m] = *(const u16x8*)&As[(wm * 64 + m * 16 + r) * 64 + (((kk * 4 + g) ^ (r & 7)) * 8)];
#pragma unroll
      for (int n = 0; n < 4; ++n)
        bq[n] = *(const u16x8*)&Bs[(wn * 64 + n * 16 + r) * 64 + (((kk * 4 + g) ^ (r & 7)) * 8)];
#pragma unroll
      for (int m = 0; m < 4; ++m)
#pragma unroll
        for (int n = 0; n < 4; ++n) acc[m][n] = mfma16(af[m], bq[n], acc[m][n]);
    }
    __syncthreads();
  }

  // epilogue: flat [t][256] stores; q/k as fp8 (unscaled), v_mod as bf16
  const int sec = bn >> 1;                       // 0=q 1=k 2=v
  const int cb = (bn & 1) * 128 + wn * 64;       // section-local col base
  float bias[4];
#pragma unroll
  for (int n = 0; n < 4; ++n) bias[n] = qkvb[sec * 256 + cb + n * 16 + r];
#pragma unroll
  for (int m = 0; m < 4; ++m) {
#pragma unroll
    for (int i = 0; i < 4; ++i) {
      int t = bm * 128 + wm * 64 + m * 16 + g * 4 + i;
      if (sec == 0) {
        u8* dst = qb8 + (size_t)t * 256 + cb;
#pragma unroll
        for (int n = 0; n < 4; ++n) dst[n * 16 + r] = f2fp8(acc[m][n][i] + bias[n]);
      } else if (sec == 1) {
        u8* dst = kb8 + (size_t)t * 256 + cb;
#pragma unroll
        for (int n = 0; n < 4; ++n) dst[n * 16 + r] = f2fp8(acc[m][n][i] + bias[n]);
      } else {
        u16* dst = vmb + (size_t)t * 256 + cb;
        const u16* xsrc = xbf + (size_t)t * 256 + cb;
#pragma unroll
        for (int n = 0; n < 4; ++n)
          dst[n * 16 + r] = f2bf(0.1f * (acc[m][n][i] + bias[n]) + bf2f(xsrc[n * 16 + r]));
      }
    }
  }
}

// ---------------- K2: attention (fp8 QK^T) + conv + combine; flat xo [t][256] ----------------
template<int HW0, int NPIX>
DEV void conv_do(const float (&in_f)[49], const float (&wreg)[49], const u16* xs,
                 int c, size_t obase, u16* __restrict__ xo){
#pragma unroll
  for (int p = 0; p < NPIX; ++p) {
    const int hw = HW0 + p;
    const int i0 = hw / 7, j0 = hw % 7;
    float a = 0.f;
#pragma unroll
    for (int di = -3; di <= 3; ++di) {
      const int ii = i0 + di;
      if (ii < 0 || ii > 6) continue;
#pragma unroll
      for (int dj = -3; dj <= 3; ++dj) {
        const int jj = j0 + dj;
        if (jj < 0 || jj > 6) continue;
        a += in_f[ii * 7 + jj] * wreg[(di + 3) * 7 + (dj + 3)];
      }
    }
    float xsv = bf2f(xs[hw * 72 + c]);
    float outv = in_f[hw] + 0.05f * xsv + a;
    xo[obase + (size_t)hw * 256] = f2bf(outv);
  }
}

__global__ __launch_bounds__(256) void k_attn(const u8* __restrict__ qb8,
                                              const u8* __restrict__ kb8,
                                              const u16* __restrict__ vmb,
                                              const float* __restrict__ weffT,
                                              u16* __restrict__ xo){
  __shared__ __align__(16) u16 smem[18432];   // per head: Vt 64*72 @hl*9216, P 64*72 @+4608
  const int bx = blockIdx.x;
  const int b = bx >> 1, hp = bx & 1;
  const int tid = threadIdx.x, lane = tid & 63, wid = tid >> 6;
  const int hl = wid >> 1, hf = wid & 1;      // head_local, half
  const int hg = hp * 2 + hl;                 // global head
  const int vto = hl * 9216, po = hl * 9216 + 4608;
  const int r = lane & 15, g = lane >> 4;
  const size_t tok0 = (size_t)b * 49;         // first token of window
  const int hc = hg * 64;                     // head channel base

  // ---- stage v transposed vT[d][key]: split across the two hf-waves ----
  {
    int c = lane;
    if (hf == 0) {
      u16 pix[24];
#pragma unroll
      for (int hw = 0; hw < 24; ++hw) pix[hw] = vmb[(tok0 + hw) * 256 + hc + c];
#pragma unroll
      for (int t2 = 0; t2 < 6; ++t2) {
        u32x2 w;
        w[0] = (unsigned)pix[4 * t2] | ((unsigned)pix[4 * t2 + 1] << 16);
        w[1] = (unsigned)pix[4 * t2 + 2] | ((unsigned)pix[4 * t2 + 3] << 16);
        *(u32x2*)&smem[vto + c * 72 + 4 * t2] = w;
      }
    } else {
      u16 pix[25];
#pragma unroll
      for (int hw = 0; hw < 25; ++hw) pix[hw] = vmb[(tok0 + 24 + hw) * 256 + hc + c];
#pragma unroll
      for (int t2 = 0; t2 < 6; ++t2) {
        u32x2 w;
        w[0] = (unsigned)pix[4 * t2] | ((unsigned)pix[4 * t2 + 1] << 16);
        w[1] = (unsigned)pix[4 * t2 + 2] | ((unsigned)pix[4 * t2 + 3] << 16);
        *(u32x2*)&smem[vto + c * 72 + 24 + 4 * t2] = w;
      }
      u32x2 wl; wl[0] = (unsigned)pix[24]; wl[1] = 0u;
      *(u32x2*)&smem[vto + c * 72 + 48] = wl;
      u32x2 z; z[0] = 0u; z[1] = 0u;
      *(u32x2*)&smem[vto + c * 72 + 52] = z;
      *(u32x2*)&smem[vto + c * 72 + 56] = z;
      *(u32x2*)&smem[vto + c * 72 + 60] = z;
    }
  }

  // ---- S = Q K^T in fp8, fragments loaded directly global->VGPR (8B each) ----
  const int mt0 = hf * 2;
  const f32x4 fz = {0.f, 0.f, 0.f, 0.f};
  f32x4 s[2][4];
#pragma unroll
  for (int m = 0; m < 2; ++m)
#pragma unroll
    for (int n = 0; n < 4; ++n) s[m][n] = fz;
  long aq[2][2], bk[4][2];
#pragma unroll
  for (int m = 0; m < 2; ++m) {
    int qrow = (mt0 + m) * 16 + r; if (qrow > 48) qrow = 48;   // junk rows -> dup, never read
    const u8* src = qb8 + (tok0 + qrow) * 256 + hc;
    aq[m][0] = *(const long*)(src + g * 8);
    aq[m][1] = *(const long*)(src + 32 + g * 8);
  }
#pragma unroll
  for (int n = 0; n < 4; ++n) {
    int krow = n * 16 + r; if (krow > 48) krow = 0;            // junk keys masked below
    const u8* src = kb8 + (tok0 + krow) * 256 + hc;
    bk[n][0] = *(const long*)(src + g * 8);
    bk[n][1] = *(const long*)(src + 32 + g * 8);
  }
#pragma unroll
  for (int kk = 0; kk < 2; ++kk)
#pragma unroll
    for (int m = 0; m < 2; ++m)
#pragma unroll
      for (int n = 0; n < 4; ++n) s[m][n] = mfma_fp8(aq[m][kk], bk[n][kk], s[m][n]);

  // ---- softmax (rows = queries), scale S by 1/8, mask cols >= 49, write P bf16 ----
#pragma unroll
  for (int m = 0; m < 2; ++m) {
#pragma unroll
    for (int i = 0; i < 4; ++i) {
      float x0 = s[m][0][i] * 0.125f, x1 = s[m][1][i] * 0.125f, x2 = s[m][2][i] * 0.125f;
      float x3 = (r >= 1) ? -1e30f : s[m][3][i] * 0.125f;
      float mx = fmaxf(fmaxf(x0, x1), fmaxf(x2, x3));
#pragma unroll
      for (int off = 1; off < 16; off <<= 1) mx = fmaxf(mx, __shfl_xor(mx, off, 64));
      float e0 = __expf(x0 - mx), e1 = __expf(x1 - mx), e2 = __expf(x2 - mx);
      float e3 = (r >= 1) ? 0.f : __expf(x3 - mx);
      float sum = e0 + e1 + e2 + e3;
#pragma unroll
      for (int off = 1; off < 16; off <<= 1) sum += __shfl_xor(sum, off, 64);
      float inv = 1.f / sum;
      int rowp = po + ((mt0 + m) * 16 + g * 4 + i) * 72;
      smem[rowp + r]       = f2bf(e0 * inv);
      smem[rowp + 16 + r]  = f2bf(e1 * inv);
      smem[rowp + 32 + r]  = f2bf(e2 * inv);
      smem[rowp + 48 + r]  = f2bf(e3 * inv);
    }
  }
  __syncthreads();   // V staged; P visible

  // ---- x_spa = P V (bf16) ----
  f32x4 o[2][4];
#pragma unroll
  for (int m = 0; m < 2; ++m)
#pragma unroll
    for (int n = 0; n < 4; ++n) o[m][n] = fz;
#pragma unroll
  for (int kk = 0; kk < 2; ++kk) {
    u16x8 pa[2], vb[4];
#pragma unroll
    for (int m = 0; m < 2; ++m) pa[m] = *(const u16x8*)&smem[po + ((mt0 + m) * 16 + r) * 72 + kk * 32 + g * 8];
#pragma unroll
    for (int n = 0; n < 4; ++n) vb[n] = *(const u16x8*)&smem[vto + (n * 16 + r) * 72 + kk * 32 + g * 8];
#pragma unroll
    for (int m = 0; m < 2; ++m)
#pragma unroll
      for (int n = 0; n < 4; ++n) o[m][n] = mfma16(pa[m], vb[n], o[m][n]);
  }
  // write x_spa (bf16) over own P rows
#pragma unroll
  for (int m = 0; m < 2; ++m)
#pragma unroll
    for (int n = 0; n < 4; ++n)
#pragma unroll
      for (int i = 0; i < 4; ++i)
        smem[po + ((mt0 + m) * 16 + g * 4 + i) * 72 + n * 16 + r] = f2bf(o[m][n][i]);
  __syncthreads();

  // ---- depthwise conv (folded 7x7) + combine + write xo flat [t][256] ----
  {
    int c = lane;
    float in_f[49];
#pragma unroll
    for (int t2 = 0; t2 < 6; ++t2) {
      u16x8 raw = *(const u16x8*)&smem[vto + c * 72 + t2 * 8];
#pragma unroll
      for (int e = 0; e < 8; ++e) in_f[t2 * 8 + e] = bf2f(raw[e]);
    }
    in_f[48] = bf2f(smem[vto + c * 72 + 48]);
    float wreg[49];
    const float* wsrc = weffT + (size_t)(hc + c) * 52;
#pragma unroll
    for (int j = 0; j < 12; ++j) {
      float4 v = *(const float4*)(wsrc + j * 4);
      wreg[j * 4] = v.x; wreg[j * 4 + 1] = v.y; wreg[j * 4 + 2] = v.z; wreg[j * 4 + 3] = v.w;
    }
    wreg[48] = wsrc[48];
    size_t obase = tok0 * 256 + hc + c;
    if (hf == 0) conv_do<0, 25>(in_f, wreg, &smem[po], c, obase, xo);
    else         conv_do<25, 24>(in_f, wreg, &smem[po], c, obase, xo);
  }
}

// ---------------- K3: FFN-in + SiLU  M=100352 N=256 K=256 (flat xo, no divisions) ----------------
__global__ __launch_bounds__(256) void k_ffn1(const u16* __restrict__ xo,
                                              const u16* __restrict__ wfi,
                                              u16* __restrict__ h){
  __shared__ __align__(16) u16 As[128 * 64];
  __shared__ __align__(16) u16 Bs[128 * 64];
  const int bid = blockIdx.x;
  const int lin = (bid & 7) * 196 + (bid >> 3);  // 1568 = 8*196
  const int bm = lin >> 1, bn = lin & 1;
  const int tid = threadIdx.x, lane = tid & 63, wid = tid >> 6;
  const int wm = wid >> 1, wn = wid & 1;
  const int r = lane & 15, g = lane >> 4;
  const int lr = lane >> 3;
  const int swz = ((lane & 7) ^ lr) * 16;
  const f32x4 fz = {0.f, 0.f, 0.f, 0.f};
  f32x4 acc[4][4];
#pragma unroll
  for (int m = 0; m < 4; ++m)
#pragma unroll
    for (int n = 0; n < 4; ++n) acc[m][n] = fz;

  const char* gA0 = (const char*)xo + (size_t)bm * 128 * 512;
  const char* gB0 = (const char*)wfi + (size_t)bn * 128 * 512;

  for (int kt = 0; kt < 4; ++kt) {
#pragma unroll
    for (int ri = 0; ri < 4; ++ri) {
      int chunk = ri * 4 + wid;
      int row = chunk * 8 + lr;
      g2l16(gA0 + (size_t)row * 512 + kt * 128 + swz, (char*)As + chunk * 1024);
      g2l16(gB0 + (size_t)row * 512 + kt * 128 + swz, (char*)Bs + chunk * 1024);
    }
    __syncthreads();
#pragma unroll
    for (int kk = 0; kk < 2; ++kk) {
      u16x8 af[4], bq[4];
#pragma unroll
      for (int m = 0; m < 4; ++m)
        af[m] = *(const u16x8*)&As[(wm * 64 + m * 16 + r) * 64 + (((kk * 4 + g) ^ (r & 7)) * 8)];
#pragma unroll
      for (int n = 0; n < 4; ++n)
        bq[n] = *(const u16x8*)&Bs[(wn * 64 + n * 16 + r) * 64 + (((kk * 4 + g) ^ (r & 7)) * 8)];
#pragma unroll
      for (int m = 0; m < 4; ++m)
#pragma unroll
        for (int n = 0; n < 4; ++n) acc[m][n] = mfma16(af[m], bq[n], acc[m][n]);
    }
    __syncthreads();
  }
#pragma unroll
  for (int m = 0; m < 4; ++m)
#pragma unroll
    for (int i = 0; i < 4; ++i) {
      int t = bm * 128 + wm * 64 + m * 16 + g * 4 + i;
      u16* dst = h + (size_t)t * 256 + bn * 128 + wn * 64;
#pragma unroll
      for (int n = 0; n < 4; ++n) {
        float v = acc[m][n][i];
        float sg = v / (1.f + __expf(-v));
        dst[n * 16 + r] = f2bf(sg);
      }
    }
}

// ---------------- K4: FFN-out + residual + LayerNorm + scatter (flat xo) ----------------
__global__ __launch_bounds__(512) void k_ffn2(const u16* __restrict__ h,
                                              const u16* __restrict__ wfo,
                                              const u16* __restrict__ xo,
                                              const float* __restrict__ lng,
                                              const float* __restrict__ lnb,
                                              float* __restrict__ out){
  __shared__ __align__(16) u16 As[128 * 64];
  __shared__ __align__(16) u16 Bs[256 * 64];
  __shared__ float red1[4][128];
  __shared__ float red2[4][128];
  const int bm = blockIdx.x;
  const int tid = threadIdx.x, lane = tid & 63, wid = tid >> 6;
  const int wm = wid >> 2, wn = wid & 3;
  const int r = lane & 15, g = lane >> 4;
  const int lr = lane >> 3;
  const int swz = ((lane & 7) ^ lr) * 16;
  const f32x4 fz = {0.f, 0.f, 0.f, 0.f};
  f32x4 acc[4][4];
#pragma unroll
  for (int m = 0; m < 4; ++m)
#pragma unroll
    for (int n = 0; n < 4; ++n) acc[m][n] = fz;

  for (int kt = 0; kt < 4; ++kt) {
#pragma unroll
    for (int ri = 0; ri < 2; ++ri) {
      int chunk = ri * 8 + wid;
      int row = chunk * 8 + lr;
      g2l16((const char*)h + (size_t)(bm * 128 + row) * 512 + kt * 128 + swz, (char*)As + chunk * 1024);
    }
#pragma unroll
    for (int ri = 0; ri < 4; ++ri) {
      int chunk = ri * 8 + wid;
      int row = chunk * 8 + lr;
      g2l16((const char*)wfo + (size_t)row * 512 + kt * 128 + swz, (char*)Bs + chunk * 1024);
    }
    __syncthreads();
#pragma unroll
    for (int kk = 0; kk < 2; ++kk) {
      u16x8 af[4], bq[4];
#pragma unroll
      for (int m = 0; m < 4; ++m)
        af[m] = *(const u16x8*)&As[(wm * 64 + m * 16 + r) * 64 + (((kk * 4 + g) ^ (r & 7)) * 8)];
#pragma unroll
      for (int n = 0; n < 4; ++n)
        bq[n] = *(const u16x8*)&Bs[(wn * 64 + n * 16 + r) * 64 + (((kk * 4 + g) ^ (r & 7)) * 8)];
#pragma unroll
      for (int m = 0; m < 4; ++m)
#pragma unroll
        for (int n = 0; n < 4; ++n) acc[m][n] = mfma16(af[m], bq[n], acc[m][n]);
    }
    __syncthreads();
  }

  float lg[4], lb[4];
#pragma unroll
  for (int n = 0; n < 4; ++n) {
    int col = wn * 64 + n * 16 + r;
    lg[n] = lng[col]; lb[n] = lnb[col];
  }
  // residual: val = 0.5*y + xo (flat [t][256])
#pragma unroll
  for (int m = 0; m < 4; ++m)
#pragma unroll
    for (int i = 0; i < 4; ++i) {
      int t = bm * 128 + wm * 64 + m * 16 + g * 4 + i;
      const u16* xsrc = xo + (size_t)t * 256;
#pragma unroll
      for (int n = 0; n < 4; ++n) {
        int col = wn * 64 + n * 16 + r;
        acc[m][n][i] = 0.5f * acc[m][n][i] + bf2f(xsrc[col]);
      }
    }
  // per-row partial sums over this wave's 64 cols
#pragma unroll
  for (int m = 0; m < 4; ++m)
#pragma unroll
    for (int i = 0; i < 4; ++i) {
      float s1 = 0.f, s2 = 0.f;
#pragma unroll
      for (int n = 0; n < 4; ++n) { float v = acc[m][n][i]; s1 += v; s2 += v * v; }
#pragma unroll
      for (int off = 1; off < 16; off <<= 1) { s1 += __shfl_xor(s1, off, 64); s2 += __shfl_xor(s2, off, 64); }
      if (r == 0) {
        int rl = wm * 64 + m * 16 + g * 4 + i;
        red1[wn][rl] = s1; red2[wn][rl] = s2;
      }
    }
  __syncthreads();
#pragma unroll
  for (int m = 0; m < 4; ++m)
#pragma unroll
    for (int i = 0; i < 4; ++i) {
      int rl = wm * 64 + m * 16 + g * 4 + i;
      float S1 = red1[0][rl] + red1[1][rl] + red1[2][rl] + red1[3][rl];
      float S2 = red2[0][rl] + red2[1][rl] + red2[2][rl] + red2[3][rl];
      float mu = S1 * (1.f / 256.f);
      float var = S2 * (1.f / 256.f) - mu * mu;
      float rstd = rsqrtf(var + 1e-5f);
      int t = bm * 128 + rl;
      int b49 = t / 49, hw = t - b49 * 49;
      size_t ob = xrow_from(b49, hw);
#pragma unroll
      for (int n = 0; n < 4; ++n) {
        int col = wn * 64 + n * 16 + r;
        out[ob + col] = (acc[m][n][i] - mu) * rstd * lg[n] + lb[n];
      }
    }
}

// ---------------- launch ----------------
extern "C" void kernel_launch(void* const* d_in, const int* in_sizes, int n_in,
                              void* d_out, int out_size, void* d_ws, size_t ws_size,
                              hipStream_t stream) {
  (void)in_sizes; (void)n_in; (void)out_size; (void)ws_size;
  const float* x     = (const float*)d_in[0];
  const float* qkvw  = (const float*)d_in[1];
  const float* qkvb  = (const float*)d_in[2];
  const float* c3    = (const float*)d_in[3];
  const float* c5    = (const float*)d_in[4];
  const float* c7    = (const float*)d_in[5];
  const float* fin   = (const float*)d_in[6];
  const float* fout  = (const float*)d_in[7];
  const float* lng   = (const float*)d_in[8];
  const float* lnb   = (const float*)d_in[9];
  float* out = (float*)d_out;
  char* ws = (char*)d_ws;

  u8*    qb8   = (u8*)(ws);                       // 25690112 B ; region reused as h by K3/K4
  u8*    kb8   = (u8*)(ws + 25690112);            // 25690112 B
  u16*   xob   = (u16*)(ws + 51380224);           // 51380224 B : xo flat [t][256]
  u16*   vmb   = (u16*)(ws + 102760448);          // 51380224 B
  u16*   wq    = (u16*)(ws + 154140672);          // 393216 B
  u16*   wfi   = (u16*)(ws + 154533888);          // 131072 B
  u16*   wfo   = (u16*)(ws + 154664960);          // 131072 B
  float* weffT = (float*)(ws + 154796032);        // 53248 B  [256ch][52]
  u16*   xbf   = (u16*)d_out;                     // scratch: 51MB bf16 x, dead before k_ffn2
  u16*   hbuf  = (u16*)(ws);                      // h aliases qb8/kb8 region (dead after k_attn)

  k_pre<<<dim3(26417), dim3(256), 0, stream>>>(x, xbf, qkvw, c3, c5, c7, fin, fout, wq, wfi, wfo, weffT);
  k_qkv<<<dim3(4704), dim3(256), 0, stream>>>(xbf, wq, qkvb, qb8, kb8, vmb);
  k_attn<<<dim3(4096), dim3(256), 0, stream>>>(qb8, kb8, vmb, weffT, xob);
  k_ffn1<<<dim3(1568), dim3(256), 0, stream>>>(xob, wfi, hbuf);
  k_ffn2<<<dim3(784), dim3(512), 0, stream>>>(hbuf, wfo, xob, lng, lnb, out);
}

// Round 14
// 256.684 us; speedup vs baseline: 1.0470x; 1.0020x over previous
//
#include <hip/hip_runtime.h>

typedef unsigned short u16;
typedef unsigned char  u8;
typedef unsigned short u16x8 __attribute__((ext_vector_type(8)));
typedef unsigned short u16x4 __attribute__((ext_vector_type(4)));
typedef unsigned int   u32x2 __attribute__((ext_vector_type(2)));
typedef short          s16x8 __attribute__((ext_vector_type(8)));
typedef float          f32x4 __attribute__((ext_vector_type(4)));

#define DEV static __device__ __forceinline__

DEV float bf2f(u16 u){ unsigned int v = ((unsigned int)u) << 16; return __builtin_bit_cast(float, v); }
DEV u16 f2bf(float f){
  unsigned int u = __builtin_bit_cast(unsigned int, f);
  u += 0x7fffu + ((u >> 16) & 1u);
  return (u16)(u >> 16);
}
DEV u8 f2fp8(float f){
  int p = __builtin_amdgcn_cvt_pk_fp8_f32(f, f, 0, false);
  return (u8)(p & 0xff);
}

DEV f32x4 mfma16(u16x8 a, u16x8 b, f32x4 c){
  return __builtin_amdgcn_mfma_f32_16x16x32_bf16(
      __builtin_bit_cast(s16x8, a), __builtin_bit_cast(s16x8, b), c, 0, 0, 0);
}
DEV f32x4 mfma_fp8(long a, long b, f32x4 c){
  return __builtin_amdgcn_mfma_f32_16x16x32_fp8_fp8(a, b, c, 0, 0, 0);
}

// async global->LDS, 16B per lane; lds dest must be wave-uniform base
DEV void g2l16(const void* g, void* l){
  __builtin_amdgcn_global_load_lds((const __attribute__((address_space(1))) void*)g,
                                   (__attribute__((address_space(3))) void*)l, 16, 0, 0);
}

// token t (windowed order) -> float offset of its 256-channel row in x / out [B,56,56,256]
DEV size_t xrow_from(int b, int hw){
  int h1 = hw / 7, w1 = hw - h1 * 7;
  return ((size_t)(((b >> 6) * 56 + h1 * 8 + ((b >> 3) & 7)) * 56 + (w1 * 8 + (b & 7)))) << 8;
}
DEV size_t xrow_off(int t){ int b = t / 49; return xrow_from(b, t - b * 49); }

// ---------------- K0: x->bf16 windowed (64B/thread) + weight prep ----------------
__global__ __launch_bounds__(256) void k_pre(const float* __restrict__ x, u16* __restrict__ xbf,
                                             const float* __restrict__ qkvw,
                                             const float* __restrict__ c3,
                                             const float* __restrict__ c5,
                                             const float* __restrict__ c7,
                                             const float* __restrict__ fin,
                                             const float* __restrict__ fout,
                                             u16* __restrict__ wq, u16* __restrict__ wfi,
                                             u16* __restrict__ wfo, float* __restrict__ weffT){
  int tid = threadIdx.x;
  if (blockIdx.x < 6272) {
    int tok = blockIdx.x * 16 + (tid >> 4);
    int c16 = (tid & 15) * 16;
    const float* src = x + xrow_off(tok) + c16;
    float4 f0 = *(const float4*)(src);
    float4 f1 = *(const float4*)(src + 4);
    float4 f2 = *(const float4*)(src + 8);
    float4 f3 = *(const float4*)(src + 12);
    u16x8 o0, o1;
    o0[0] = f2bf(f0.x); o0[1] = f2bf(f0.y); o0[2] = f2bf(f0.z); o0[3] = f2bf(f0.w);
    o0[4] = f2bf(f1.x); o0[5] = f2bf(f1.y); o0[6] = f2bf(f1.z); o0[7] = f2bf(f1.w);
    o1[0] = f2bf(f2.x); o1[1] = f2bf(f2.y); o1[2] = f2bf(f2.z); o1[3] = f2bf(f2.w);
    o1[4] = f2bf(f3.x); o1[5] = f2bf(f3.y); o1[6] = f2bf(f3.z); o1[7] = f2bf(f3.w);
    u16* dst = xbf + (size_t)tok * 256 + c16;
    *(u16x8*)(dst) = o0;
    *(u16x8*)(dst + 8) = o1;
    return;
  }
  int id = (blockIdx.x - 6272) * 256 + tid;
  if (id < 196608) { wq[id] = f2bf(qkvw[id]); return; }
  id -= 196608;
  if (id < 65536) { wfi[id] = f2bf(fin[id]); return; }
  id -= 65536;
  if (id < 65536) { wfo[id] = f2bf(fout[id]); return; }
  id -= 65536;
  if (id < 12544) {
    int c = id / 49, t = id - c * 49;
    int di = t / 7 - 3, dj = t % 7 - 3;
    float s = c7[c * 49 + t];
    if (di >= -2 && di <= 2 && dj >= -2 && dj <= 2) s += c5[c * 25 + (di + 2) * 5 + (dj + 2)];
    if (di >= -1 && di <= 1 && dj >= -1 && dj <= 1) s += c3[c * 9 + (di + 1) * 3 + (dj + 1)];
    weffT[c * 52 + t] = 0.05f * s;   // BETA*0.25 folded; [channel][49 taps], stride 52
  }
}

// ---------------- K1: QKV GEMM  M=100352 N=768 K=256 (q/k -> fp8, v -> bf16) ----------------
__global__ __launch_bounds__(256) void k_qkv(const u16* __restrict__ xbf,
                                             const u16* __restrict__ wq,
                                             const float* __restrict__ qkvb,
                                             u8* __restrict__ qb8, u8* __restrict__ kb8,
                                             u16* __restrict__ vmb){
  __shared__ __align__(16) u16 As[128 * 64];
  __shared__ __align__(16) u16 Bs[128 * 64];
  const int bid = blockIdx.x;
  const int lin = (bid & 7) * 588 + (bid >> 3);  // XCD-chunk swizzle (4704 = 8*588)
  const int bm = lin / 6, bn = lin - bm * 6;
  const int tid = threadIdx.x, lane = tid & 63, wid = tid >> 6;
  const int wm = wid >> 1, wn = wid & 1;
  const int r = lane & 15, g = lane >> 4;
  const int lr = lane >> 3;
  const int swz = ((lane & 7) ^ lr) * 16;        // pre-swizzled global source block
  const f32x4 fz = {0.f, 0.f, 0.f, 0.f};
  f32x4 acc[4][4];
#pragma unroll
  for (int m = 0; m < 4; ++m)
#pragma unroll
    for (int n = 0; n < 4; ++n) acc[m][n] = fz;

  const char* gA0 = (const char*)xbf + (size_t)bm * 128 * 512;
  const char* gB0 = (const char*)wq  + (size_t)bn * 128 * 512;

  for (int kt = 0; kt < 4; ++kt) {
#pragma unroll
    for (int ri = 0; ri < 4; ++ri) {
      int chunk = ri * 4 + wid;
      int row = chunk * 8 + lr;
      g2l16(gA0 + (size_t)row * 512 + kt * 128 + swz, (char*)As + chunk * 1024);
      g2l16(gB0 + (size_t)row * 512 + kt * 128 + swz, (char*)Bs + chunk * 1024);
    }
    __syncthreads();
#pragma unroll
    for (int kk = 0; kk < 2; ++kk) {
      u16x8 af[4], bq[4];
#pragma unroll
      for (int m = 0; m < 4; ++m)
        af[m] = *(const u16x8*)&As[(wm * 64 + m * 16 + r) * 64 + (((kk * 4 + g) ^ (r & 7)) * 8)];
#pragma unroll
      for (int n = 0; n < 4; ++n)
        bq[n] = *(const u16x8*)&Bs[(wn * 64 + n * 16 + r) * 64 + (((kk * 4 + g) ^ (r & 7)) * 8)];
#pragma unroll
      for (int m = 0; m < 4; ++m)
#pragma unroll
        for (int n = 0; n < 4; ++n) acc[m][n] = mfma16(af[m], bq[n], acc[m][n]);
    }
    __syncthreads();
  }

  // epilogue: flat [t][256] stores; q/k as fp8 (unscaled), v_mod as bf16
  const int sec = bn >> 1;                       // 0=q 1=k 2=v
  const int cb = (bn & 1) * 128 + wn * 64;       // section-local col base
  float bias[4];
#pragma unroll
  for (int n = 0; n < 4; ++n) bias[n] = qkvb[sec * 256 + cb + n * 16 + r];
#pragma unroll
  for (int m = 0; m < 4; ++m) {
#pragma unroll
    for (int i = 0; i < 4; ++i) {
      int t = bm * 128 + wm * 64 + m * 16 + g * 4 + i;
      if (sec == 0) {
        u8* dst = qb8 + (size_t)t * 256 + cb;
#pragma unroll
        for (int n = 0; n < 4; ++n) dst[n * 16 + r] = f2fp8(acc[m][n][i] + bias[n]);
      } else if (sec == 1) {
        u8* dst = kb8 + (size_t)t * 256 + cb;
#pragma unroll
        for (int n = 0; n < 4; ++n) dst[n * 16 + r] = f2fp8(acc[m][n][i] + bias[n]);
      } else {
        u16* dst = vmb + (size_t)t * 256 + cb;
        const u16* xsrc = xbf + (size_t)t * 256 + cb;
#pragma unroll
        for (int n = 0; n < 4; ++n)
          dst[n * 16 + r] = f2bf(0.1f * (acc[m][n][i] + bias[n]) + bf2f(xsrc[n * 16 + r]));
      }
    }
  }
}

// ---------------- K2: attention (fp8 QK^T) + conv + combine; flat xo [t][256] ----------------
template<int HW0, int NPIX>
DEV void conv_do(const float (&in_f)[49], const float (&wreg)[49], const u16* xs,
                 int c, size_t obase, u16* __restrict__ xo){
#pragma unroll
  for (int p = 0; p < NPIX; ++p) {
    const int hw = HW0 + p;
    const int i0 = hw / 7, j0 = hw % 7;
    float a = 0.f;
#pragma unroll
    for (int di = -3; di <= 3; ++di) {
      const int ii = i0 + di;
      if (ii < 0 || ii > 6) continue;
#pragma unroll
      for (int dj = -3; dj <= 3; ++dj) {
        const int jj = j0 + dj;
        if (jj < 0 || jj > 6) continue;
        a += in_f[ii * 7 + jj] * wreg[(di + 3) * 7 + (dj + 3)];
      }
    }
    float xsv = bf2f(xs[hw * 72 + c]);
    float outv = in_f[hw] + 0.05f * xsv + a;
    xo[obase + (size_t)hw * 256] = f2bf(outv);
  }
}

__global__ __launch_bounds__(256) void k_attn(const u8* __restrict__ qb8,
                                              const u8* __restrict__ kb8,
                                              const u16* __restrict__ vmb,
                                              const float* __restrict__ weffT,
                                              u16* __restrict__ xo){
  __shared__ __align__(16) u16 smem[18432];   // per head: Vt 64*72 @hl*9216, P 64*72 @+4608
  const int bx = blockIdx.x;
  const int b = bx >> 1, hp = bx & 1;
  const int tid = threadIdx.x, lane = tid & 63, wid = tid >> 6;
  const int hl = wid >> 1, hf = wid & 1;      // head_local, half
  const int hg = hp * 2 + hl;                 // global head
  const int vto = hl * 9216, po = hl * 9216 + 4608;
  const int r = lane & 15, g = lane >> 4;
  const size_t tok0 = (size_t)b * 49;         // first token of window
  const int hc = hg * 64;                     // head channel base

  // ---- stage v transposed vT[d][key]: split across the two hf-waves ----
  {
    int c = lane;
    if (hf == 0) {
      u16 pix[24];
#pragma unroll
      for (int hw = 0; hw < 24; ++hw) pix[hw] = vmb[(tok0 + hw) * 256 + hc + c];
#pragma unroll
      for (int t2 = 0; t2 < 6; ++t2) {
        u32x2 w;
        w[0] = (unsigned)pix[4 * t2] | ((unsigned)pix[4 * t2 + 1] << 16);
        w[1] = (unsigned)pix[4 * t2 + 2] | ((unsigned)pix[4 * t2 + 3] << 16);
        *(u32x2*)&smem[vto + c * 72 + 4 * t2] = w;
      }
    } else {
      u16 pix[25];
#pragma unroll
      for (int hw = 0; hw < 25; ++hw) pix[hw] = vmb[(tok0 + 24 + hw) * 256 + hc + c];
#pragma unroll
      for (int t2 = 0; t2 < 6; ++t2) {
        u32x2 w;
        w[0] = (unsigned)pix[4 * t2] | ((unsigned)pix[4 * t2 + 1] << 16);
        w[1] = (unsigned)pix[4 * t2 + 2] | ((unsigned)pix[4 * t2 + 3] << 16);
        *(u32x2*)&smem[vto + c * 72 + 24 + 4 * t2] = w;
      }
      u32x2 wl; wl[0] = (unsigned)pix[24]; wl[1] = 0u;
      *(u32x2*)&smem[vto + c * 72 + 48] = wl;
      u32x2 z; z[0] = 0u; z[1] = 0u;
      *(u32x2*)&smem[vto + c * 72 + 52] = z;
      *(u32x2*)&smem[vto + c * 72 + 56] = z;
      *(u32x2*)&smem[vto + c * 72 + 60] = z;
    }
  }

  // ---- S = Q K^T in fp8, fragments loaded directly global->VGPR (8B each) ----
  const int mt0 = hf * 2;
  const f32x4 fz = {0.f, 0.f, 0.f, 0.f};
  f32x4 s[2][4];
#pragma unroll
  for (int m = 0; m < 2; ++m)
#pragma unroll
    for (int n = 0; n < 4; ++n) s[m][n] = fz;
  long aq[2][2], bk[4][2];
#pragma unroll
  for (int m = 0; m < 2; ++m) {
    int qrow = (mt0 + m) * 16 + r; if (qrow > 48) qrow = 48;   // junk rows -> dup, never read
    const u8* src = qb8 + (tok0 + qrow) * 256 + hc;
    aq[m][0] = *(const long*)(src + g * 8);
    aq[m][1] = *(const long*)(src + 32 + g * 8);
  }
#pragma unroll
  for (int n = 0; n < 4; ++n) {
    int krow = n * 16 + r; if (krow > 48) krow = 0;            // junk keys masked below
    const u8* src = kb8 + (tok0 + krow) * 256 + hc;
    bk[n][0] = *(const long*)(src + g * 8);
    bk[n][1] = *(const long*)(src + 32 + g * 8);
  }
#pragma unroll
  for (int kk = 0; kk < 2; ++kk)
#pragma unroll
    for (int m = 0; m < 2; ++m)
#pragma unroll
      for (int n = 0; n < 4; ++n) s[m][n] = mfma_fp8(aq[m][kk], bk[n][kk], s[m][n]);

  // ---- softmax (rows = queries), scale S by 1/8, mask cols >= 49, write P bf16 ----
#pragma unroll
  for (int m = 0; m < 2; ++m) {
#pragma unroll
    for (int i = 0; i < 4; ++i) {
      float x0 = s[m][0][i] * 0.125f, x1 = s[m][1][i] * 0.125f, x2 = s[m][2][i] * 0.125f;
      float x3 = (r >= 1) ? -1e30f : s[m][3][i] * 0.125f;
      float mx = fmaxf(fmaxf(x0, x1), fmaxf(x2, x3));
#pragma unroll
      for (int off = 1; off < 16; off <<= 1) mx = fmaxf(mx, __shfl_xor(mx, off, 64));
      float e0 = __expf(x0 - mx), e1 = __expf(x1 - mx), e2 = __expf(x2 - mx);
      float e3 = (r >= 1) ? 0.f : __expf(x3 - mx);
      float sum = e0 + e1 + e2 + e3;
#pragma unroll
      for (int off = 1; off < 16; off <<= 1) sum += __shfl_xor(sum, off, 64);
      float inv = 1.f / sum;
      int rowp = po + ((mt0 + m) * 16 + g * 4 + i) * 72;
      smem[rowp + r]       = f2bf(e0 * inv);
      smem[rowp + 16 + r]  = f2bf(e1 * inv);
      smem[rowp + 32 + r]  = f2bf(e2 * inv);
      smem[rowp + 48 + r]  = f2bf(e3 * inv);
    }
  }
  __syncthreads();   // V staged; P visible

  // ---- x_spa = P V (bf16) ----
  f32x4 o[2][4];
#pragma unroll
  for (int m = 0; m < 2; ++m)
#pragma unroll
    for (int n = 0; n < 4; ++n) o[m][n] = fz;
#pragma unroll
  for (int kk = 0; kk < 2; ++kk) {
    u16x8 pa[2], vb[4];
#pragma unroll
    for (int m = 0; m < 2; ++m) pa[m] = *(const u16x8*)&smem[po + ((mt0 + m) * 16 + r) * 72 + kk * 32 + g * 8];
#pragma unroll
    for (int n = 0; n < 4; ++n) vb[n] = *(const u16x8*)&smem[vto + (n * 16 + r) * 72 + kk * 32 + g * 8];
#pragma unroll
    for (int m = 0; m < 2; ++m)
#pragma unroll
      for (int n = 0; n < 4; ++n) o[m][n] = mfma16(pa[m], vb[n], o[m][n]);
  }
  // write x_spa (bf16) over own P rows
#pragma unroll
  for (int m = 0; m < 2; ++m)
#pragma unroll
    for (int n = 0; n < 4; ++n)
#pragma unroll
      for (int i = 0; i < 4; ++i)
        smem[po + ((mt0 + m) * 16 + g * 4 + i) * 72 + n * 16 + r] = f2bf(o[m][n][i]);
  __syncthreads();

  // ---- depthwise conv (folded 7x7) + combine + write xo flat [t][256] ----
  {
    int c = lane;
    float in_f[49];
#pragma unroll
    for (int t2 = 0; t2 < 6; ++t2) {
      u16x8 raw = *(const u16x8*)&smem[vto + c * 72 + t2 * 8];
#pragma unroll
      for (int e = 0; e < 8; ++e) in_f[t2 * 8 + e] = bf2f(raw[e]);
    }
    in_f[48] = bf2f(smem[vto + c * 72 + 48]);
    float wreg[49];
    const float* wsrc = weffT + (size_t)(hc + c) * 52;
#pragma unroll
    for (int j = 0; j < 12; ++j) {
      float4 v = *(const float4*)(wsrc + j * 4);
      wreg[j * 4] = v.x; wreg[j * 4 + 1] = v.y; wreg[j * 4 + 2] = v.z; wreg[j * 4 + 3] = v.w;
    }
    wreg[48] = wsrc[48];
    size_t obase = tok0 * 256 + hc + c;
    if (hf == 0) conv_do<0, 25>(in_f, wreg, &smem[po], c, obase, xo);
    else         conv_do<25, 24>(in_f, wreg, &smem[po], c, obase, xo);
  }
}

// ---------------- K3: FFN-in + SiLU  M=100352 N=256 K=256 (flat xo, no divisions) ----------------
__global__ __launch_bounds__(256) void k_ffn1(const u16* __restrict__ xo,
                                              const u16* __restrict__ wfi,
                                              u16* __restrict__ h){
  __shared__ __align__(16) u16 As[128 * 64];
  __shared__ __align__(16) u16 Bs[128 * 64];
  const int bid = blockIdx.x;
  const int lin = (bid & 7) * 196 + (bid >> 3);  // 1568 = 8*196
  const int bm = lin >> 1, bn = lin & 1;
  const int tid = threadIdx.x, lane = tid & 63, wid = tid >> 6;
  const int wm = wid >> 1, wn = wid & 1;
  const int r = lane & 15, g = lane >> 4;
  const int lr = lane >> 3;
  const int swz = ((lane & 7) ^ lr) * 16;
  const f32x4 fz = {0.f, 0.f, 0.f, 0.f};
  f32x4 acc[4][4];
#pragma unroll
  for (int m = 0; m < 4; ++m)
#pragma unroll
    for (int n = 0; n < 4; ++n) acc[m][n] = fz;

  const char* gA0 = (const char*)xo + (size_t)bm * 128 * 512;
  const char* gB0 = (const char*)wfi + (size_t)bn * 128 * 512;

  for (int kt = 0; kt < 4; ++kt) {
#pragma unroll
    for (int ri = 0; ri < 4; ++ri) {
      int chunk = ri * 4 + wid;
      int row = chunk * 8 + lr;
      g2l16(gA0 + (size_t)row * 512 + kt * 128 + swz, (char*)As + chunk * 1024);
      g2l16(gB0 + (size_t)row * 512 + kt * 128 + swz, (char*)Bs + chunk * 1024);
    }
    __syncthreads();
#pragma unroll
    for (int kk = 0; kk < 2; ++kk) {
      u16x8 af[4], bq[4];
#pragma unroll
      for (int m = 0; m < 4; ++m)
        af[m] = *(const u16x8*)&As[(wm * 64 + m * 16 + r) * 64 + (((kk * 4 + g) ^ (r & 7)) * 8)];
#pragma unroll
      for (int n = 0; n < 4; ++n)
        bq[n] = *(const u16x8*)&Bs[(wn * 64 + n * 16 + r) * 64 + (((kk * 4 + g) ^ (r & 7)) * 8)];
#pragma unroll
      for (int m = 0; m < 4; ++m)
#pragma unroll
        for (int n = 0; n < 4; ++n) acc[m][n] = mfma16(af[m], bq[n], acc[m][n]);
    }
    __syncthreads();
  }
#pragma unroll
  for (int m = 0; m < 4; ++m)
#pragma unroll
    for (int i = 0; i < 4; ++i) {
      int t = bm * 128 + wm * 64 + m * 16 + g * 4 + i;
      u16* dst = h + (size_t)t * 256 + bn * 128 + wn * 64;
#pragma unroll
      for (int n = 0; n < 4; ++n) {
        float v = acc[m][n][i];
        float sg = v / (1.f + __expf(-v));
        dst[n * 16 + r] = f2bf(sg);
      }
    }
}

// ---------------- K4: FFN-out + residual + LayerNorm + scatter (flat xo) ----------------
__global__ __launch_bounds__(512) void k_ffn2(const u16* __restrict__ h,
                                              const u16* __restrict__ wfo,
                                              const u16* __restrict__ xo,
                                              const float* __restrict__ lng,
                                              const float* __restrict__ lnb,
                                              float* __restrict__ out){
  __shared__ __align__(16) u16 As[128 * 64];
  __shared__ __align__(16) u16 Bs[256 * 64];
  __shared__ float red1[4][128];
  __shared__ float red2[4][128];
  const int bm = blockIdx.x;
  const int tid = threadIdx.x, lane = tid & 63, wid = tid >> 6;
  const int wm = wid >> 2, wn = wid & 3;
  const int r = lane & 15, g = lane >> 4;
  const int lr = lane >> 3;
  const int swz = ((lane & 7) ^ lr) * 16;
  const f32x4 fz = {0.f, 0.f, 0.f, 0.f};
  f32x4 acc[4][4];
#pragma unroll
  for (int m = 0; m < 4; ++m)
#pragma unroll
    for (int n = 0; n < 4; ++n) acc[m][n] = fz;

  for (int kt = 0; kt < 4; ++kt) {
#pragma unroll
    for (int ri = 0; ri < 2; ++ri) {
      int chunk = ri * 8 + wid;
      int row = chunk * 8 + lr;
      g2l16((const char*)h + (size_t)(bm * 128 + row) * 512 + kt * 128 + swz, (char*)As + chunk * 1024);
    }
#pragma unroll
    for (int ri = 0; ri < 4; ++ri) {
      int chunk = ri * 8 + wid;
      int row = chunk * 8 + lr;
      g2l16((const char*)wfo + (size_t)row * 512 + kt * 128 + swz, (char*)Bs + chunk * 1024);
    }
    __syncthreads();
#pragma unroll
    for (int kk = 0; kk < 2; ++kk) {
      u16x8 af[4], bq[4];
#pragma unroll
      for (int m = 0; m < 4; ++m)
        af[m] = *(const u16x8*)&As[(wm * 64 + m * 16 + r) * 64 + (((kk * 4 + g) ^ (r & 7)) * 8)];
#pragma unroll
      for (int n = 0; n < 4; ++n)
        bq[n] = *(const u16x8*)&Bs[(wn * 64 + n * 16 + r) * 64 + (((kk * 4 + g) ^ (r & 7)) * 8)];
#pragma unroll
      for (int m = 0; m < 4; ++m)
#pragma unroll
        for (int n = 0; n < 4; ++n) acc[m][n] = mfma16(af[m], bq[n], acc[m][n]);
    }
    __syncthreads();
  }

  float lg[4], lb[4];
#pragma unroll
  for (int n = 0; n < 4; ++n) {
    int col = wn * 64 + n * 16 + r;
    lg[n] = lng[col]; lb[n] = lnb[col];
  }
  // residual: val = 0.5*y + xo (flat [t][256])
#pragma unroll
  for (int m = 0; m < 4; ++m)
#pragma unroll
    for (int i = 0; i < 4; ++i) {
      int t = bm * 128 + wm * 64 + m * 16 + g * 4 + i;
      const u16* xsrc = xo + (size_t)t * 256;
#pragma unroll
      for (int n = 0; n < 4; ++n) {
        int col = wn * 64 + n * 16 + r;
        acc[m][n][i] = 0.5f * acc[m][n][i] + bf2f(xsrc[col]);
      }
    }
  // per-row partial sums over this wave's 64 cols
#pragma unroll
  for (int m = 0; m < 4; ++m)
#pragma unroll
    for (int i = 0; i < 4; ++i) {
      float s1 = 0.f, s2 = 0.f;
#pragma unroll
      for (int n = 0; n < 4; ++n) { float v = acc[m][n][i]; s1 += v; s2 += v * v; }
#pragma unroll
      for (int off = 1; off < 16; off <<= 1) { s1 += __shfl_xor(s1, off, 64); s2 += __shfl_xor(s2, off, 64); }
      if (r == 0) {
        int rl = wm * 64 + m * 16 + g * 4 + i;
        red1[wn][rl] = s1; red2[wn][rl] = s2;
      }
    }
  __syncthreads();
#pragma unroll
  for (int m = 0; m < 4; ++m)
#pragma unroll
    for (int i = 0; i < 4; ++i) {
      int rl = wm * 64 + m * 16 + g * 4 + i;
      float S1 = red1[0][rl] + red1[1][rl] + red1[2][rl] + red1[3][rl];
      float S2 = red2[0][rl] + red2[1][rl] + red2[2][rl] + red2[3][rl];
      float mu = S1 * (1.f / 256.f);
      float var = S2 * (1.f / 256.f) - mu * mu;
      float rstd = rsqrtf(var + 1e-5f);
      int t = bm * 128 + rl;
      int b49 = t / 49, hw = t - b49 * 49;
      size_t ob = xrow_from(b49, hw);
#pragma unroll
      for (int n = 0; n < 4; ++n) {
        int col = wn * 64 + n * 16 + r;
        out[ob + col] = (acc[m][n][i] - mu) * rstd * lg[n] + lb[n];
      }
    }
}

// ---------------- launch ----------------
extern "C" void kernel_launch(void* const* d_in, const int* in_sizes, int n_in,
                              void* d_out, int out_size, void* d_ws, size_t ws_size,
                              hipStream_t stream) {
  (void)in_sizes; (void)n_in; (void)out_size; (void)ws_size;
  const float* x     = (const float*)d_in[0];
  const float* qkvw  = (const float*)d_in[1];
  const float* qkvb  = (const float*)d_in[2];
  const float* c3    = (const float*)d_in[3];
  const float* c5    = (const float*)d_in[4];
  const float* c7    = (const float*)d_in[5];
  const float* fin   = (const float*)d_in[6];
  const float* fout  = (const float*)d_in[7];
  const float* lng   = (const float*)d_in[8];
  const float* lnb   = (const float*)d_in[9];
  float* out = (float*)d_out;
  char* ws = (char*)d_ws;

  u8*    qb8   = (u8*)(ws);                       // 25690112 B ; region reused as h by K3/K4
  u8*    kb8   = (u8*)(ws + 25690112);            // 25690112 B
  u16*   xob   = (u16*)(ws + 51380224);           // 51380224 B : xo flat [t][256]
  u16*   vmb   = (u16*)(ws + 102760448);          // 51380224 B
  u16*   wq    = (u16*)(ws + 154140672);          // 393216 B
  u16*   wfi   = (u16*)(ws + 154533888);          // 131072 B
  u16*   wfo   = (u16*)(ws + 154664960);          // 131072 B
  float* weffT = (float*)(ws + 154796032);        // 53248 B  [256ch][52]
  u16*   xbf   = (u16*)d_out;                     // scratch: 51MB bf16 x, dead before k_ffn2
  u16*   hbuf  = (u16*)(ws);                      // h aliases qb8/kb8 region (dead after k_attn)

  k_pre<<<dim3(7601), dim3(256), 0, stream>>>(x, xbf, qkvw, c3, c5, c7, fin, fout, wq, wfi, wfo, weffT);
  k_qkv<<<dim3(4704), dim3(256), 0, stream>>>(xbf, wq, qkvb, qb8, kb8, vmb);
  k_attn<<<dim3(4096), dim3(256), 0, stream>>>(qb8, kb8, vmb, weffT, xob);
  k_ffn1<<<dim3(1568), dim3(256), 0, stream>>>(xob, wfi, hbuf);
  k_ffn2<<<dim3(784), dim3(512), 0, stream>>>(hbuf, wfo, xob, lng, lnb, out);
}